// Round 22
// baseline (194.859 us; speedup 1.0000x reference)
//
#include <hip/hip_runtime.h>
#include <math.h>

#define PI_F 3.14159265358979323846f

typedef __attribute__((ext_vector_type(8))) _Float16 half8;
typedef __attribute__((ext_vector_type(4))) _Float16 half4;
typedef __attribute__((ext_vector_type(4))) float f32x4;

// ---------------------------------------------------------------------------
// Unified prep kernel, grid 3153x256:
//  [0,2380)    x (256,3,64,64) fp32 -> X4P (256,70,68,4) fp16, zero border
//  [2380,2640) conv weight transforms (channel-blocked fp16)
//  [2640,3152) fc1 weight transform (NCHW-k -> NHWC-k fp16)
//  [3152]      quantum prep: 60 Rot matrices + 6x1024 u16 perm table
// ---------------------------------------------------------------------------
__global__ __launch_bounds__(256) void prep_kernel(
    const float* __restrict__ x, _Float16* __restrict__ X4P,
    const float* __restrict__ w1, const float* __restrict__ w2,
    const float* __restrict__ w3, const float* __restrict__ w4,
    _Float16* __restrict__ t1, _Float16* __restrict__ t2,
    _Float16* __restrict__ t3, _Float16* __restrict__ t4,
    const float* __restrict__ f1w, _Float16* __restrict__ w1t,
    const float* __restrict__ qw, float* __restrict__ rotm,
    unsigned short* __restrict__ perm)
{
    const int b = blockIdx.x;
    const int t = threadIdx.x;
    if (b < 2380) {
        int pp = (b * 256 + t) * 2;          // 2 pixels per thread
        half8 o;
        #pragma unroll
        for (int j = 0; j < 2; ++j) {
            int p = pp + j;
            int n = p / 4760;
            int rem = p - n * 4760;
            int yp = rem / 68, xp = rem - (rem / 68) * 68;
            int gy = yp - 2, gx = xp - 2;
            float v0 = 0.f, v1 = 0.f, v2 = 0.f;
            if (gy >= 0 && gy < 64 && gx >= 0 && gx < 64) {
                const float* xb = x + (size_t)n * 12288 + gy * 64 + gx;
                v0 = xb[0]; v1 = xb[4096]; v2 = xb[8192];
            }
            o[j * 4 + 0] = (_Float16)v0;
            o[j * 4 + 1] = (_Float16)v1;
            o[j * 4 + 2] = (_Float16)v2;
            o[j * 4 + 3] = (_Float16)0.f;
        }
        *(half8*)&X4P[(size_t)pp * 4] = o;
    } else if (b < 2640) {
        int idx = (b - 2380) * 256 + t;
        if (idx < 9216) {               // conv2: K=288, 1 group
            int j = idx & 7, co = (idx >> 3) & 31, k8 = idx >> 8;
            int k = k8 * 8 + j, tap = k >> 5, ci = k & 31;
            t2[idx] = (_Float16)w2[(size_t)(co * 32 + ci) * 9 + tap];
        } else if (idx < 27648) {       // conv3: 2 cout groups
            int e = idx - 9216;
            int j = e & 7, co = (e >> 3) & 31, r = e >> 8;
            int k8 = r % 36, gg = r / 36;
            int k = k8 * 8 + j, tap = k >> 5, ci = k & 31;
            t3[e] = (_Float16)w3[(size_t)((gg * 32 + co) * 32 + ci) * 9 + tap];
        } else if (idx < 64512) {       // conv4: 2 cout groups x 2 ci-chunks
            int e = idx - 27648;
            int j = e & 7, co = (e >> 3) & 31, r = e >> 8;
            int k8 = r % 36, gc = r / 36;
            int g = gc >> 1, cc = gc & 1;
            int kl = k8 * 8 + j, tap = kl >> 5, ci = cc * 32 + (kl & 31);
            t4[e] = (_Float16)w4[(size_t)((g * 32 + co) * 64 + ci) * 9 + tap];
        } else if (idx < 66560) {       // conv1: K=64 padded
            int e = idx - 64512;
            int j = e & 7, co = (e >> 3) & 31, k8 = e >> 8;
            int k = k8 * 8 + j, tap = k >> 2, ci = k & 3;
            t1[e] = (_Float16)((tap < 9 && ci < 3) ? w1[(size_t)(co * 3 + ci) * 9 + tap] : 0.f);
        }
    } else if (b < 3152) {
        __shared__ float lds[64][65];
        int b2 = b - 2640;
        const int yx0 = (b2 & 3) * 64;
        const int j = b2 >> 2;
        #pragma unroll
        for (int i = 0; i < 16; ++i) {
            int idx = t + 256 * i;
            int c = idx >> 6, yxl = idx & 63;
            lds[c][yxl] = f1w[(size_t)j * 16384 + c * 256 + yx0 + yxl];
        }
        __syncthreads();
        #pragma unroll
        for (int i = 0; i < 2; ++i) {
            int idx = t + 256 * i;
            int yxl = idx >> 3, c8 = idx & 7;
            half8 h;
            #pragma unroll
            for (int jj = 0; jj < 8; ++jj)
                h[jj] = (_Float16)lds[c8 * 8 + jj][yxl];
            *(half8*)&w1t[(size_t)j * 16384 + (size_t)(yx0 + yxl) * 64 + c8 * 8] = h;
        }
    } else {
        if (t < 60) {
            float phi = qw[t * 3], th = qw[t * 3 + 1], om = qw[t * 3 + 2];
            float c = cosf(0.5f * th), s = sinf(0.5f * th);
            float apo = 0.5f * (phi + om), amo = 0.5f * (phi - om);
            float cpo = cosf(apo), spo = sinf(apo);
            float cmo = cosf(amo), smo = sinf(amo);
            rotm[t * 8 + 0] = cpo * c;  rotm[t * 8 + 1] = -spo * c;
            rotm[t * 8 + 2] = -cmo * s; rotm[t * 8 + 3] = -smo * s;
            rotm[t * 8 + 4] = cmo * s;  rotm[t * 8 + 5] = -smo * s;
            rotm[t * 8 + 6] = cpo * c;  rotm[t * 8 + 7] = spo * c;
        }
        for (int e = t; e < 6144; e += 256) {
            int layer = e >> 10, i = e & 1023;
            int r = layer % 9 + 1;
            int jdx = i;
            for (int w = 9; w >= 0; --w) {
                int tt = (w + r) % 10;
                int pc = 9 - w, pt_ = 9 - tt;
                jdx ^= ((jdx >> pc) & 1) << pt_;
            }
            perm[e] = (unsigned short)jdx;
        }
    }
}

// ---------------------------------------------------------------------------
// conv1: conv1 via MFMA from X4P -> Yg = fp16(conv1+bias) NHWC (256,64,64,32)
// + BN1 partials. Y packed through LDS for coalesced half8 stores.
// ---------------------------------------------------------------------------
__global__ __launch_bounds__(256) void conv1_stats_kernel(
    const _Float16* __restrict__ X4P, const _Float16* __restrict__ w1m,
    const float* __restrict__ bias, _Float16* __restrict__ Yg,
    float* __restrict__ partials)
{
    constexpr int TC = 66, TR = 6;
    constexpr int NPIX = (TR + 1) * TC;     // 462
    __shared__ __align__(16) _Float16 s_in[NPIX * 4];
    __shared__ __align__(16) _Float16 s_w[2048];
    __shared__ __align__(16) _Float16 s_y[256 * 32];   // 16 KB
    __shared__ float s_red[64];

    const int t = threadIdx.x;
    const int row0 = blockIdx.x * 4;
    const int n = blockIdx.z;

    *(half8*)&s_w[t * 8] = *(const half8*)&w1m[t * 8];

    for (int p = t; p < NPIX; p += 256) {
        int col = p % TC, r = p / TC;
        uint2 u = make_uint2(0u, 0u);
        if (r < TR) {
            // image (gy,gx) = (row0+r-1, col-1) -> padded (row0+r+1, col+1)
            size_t pb = ((size_t)(n * 70 + row0 + r + 1) * 68 + col + 1) * 4;
            u = *(const uint2*)&X4P[pb];
        }
        *(uint2*)&s_in[p * 4] = u;
    }
    if (t < 64) s_red[t] = 0.f;
    __syncthreads();

    const int w = t >> 6, l = t & 63;
    const int lm = l & 15, lg = l >> 4;
    int pA[4];
    #pragma unroll
    for (int f = 0; f < 4; ++f) {
        int m = w * 64 + f * 16 + lm;
        pA[f] = (m >> 6) * TC + (m & 63);
    }
    f32x4 zero4 = {0.f, 0.f, 0.f, 0.f};
    f32x4 acc[4][2];
    #pragma unroll
    for (int f = 0; f < 4; ++f) { acc[f][0] = zero4; acc[f][1] = zero4; }

    {
        const int t0 = lg * 2;
        const int off0 = (t0 / 3) * TC + (t0 % 3);
        const int off1 = ((t0 + 1) / 3) * TC + ((t0 + 1) % 3);
        half8 b0 = *(const half8*)&s_w[(lg * 32 + lm) * 8];
        half8 b1 = *(const half8*)&s_w[(lg * 32 + 16 + lm) * 8];
        #pragma unroll
        for (int f = 0; f < 4; ++f) {
            half4 alo = *(const half4*)&s_in[(pA[f] + off0) * 4];
            half4 ahi = *(const half4*)&s_in[(pA[f] + off1) * 4];
            half8 a;
            #pragma unroll
            for (int j = 0; j < 4; ++j) { a[j] = alo[j]; a[4 + j] = ahi[j]; }
            acc[f][0] = __builtin_amdgcn_mfma_f32_16x16x32_f16(a, b0, acc[f][0], 0, 0, 0);
            acc[f][1] = __builtin_amdgcn_mfma_f32_16x16x32_f16(a, b1, acc[f][1], 0, 0, 0);
        }
    }
    {
        half8 b0 = *(const half8*)&s_w[((4 + lg) * 32 + lm) * 8];
        half8 b1 = *(const half8*)&s_w[((4 + lg) * 32 + 16 + lm) * 8];
        #pragma unroll
        for (int f = 0; f < 4; ++f) {
            half8 a;
            #pragma unroll
            for (int j = 0; j < 8; ++j) a[j] = (_Float16)0.f;
            if (lg == 0) {
                half4 alo = *(const half4*)&s_in[(pA[f] + 134) * 4];
                half4 ahi = *(const half4*)&s_in[(pA[f] + 198) * 4];
                #pragma unroll
                for (int j = 0; j < 4; ++j) { a[j] = alo[j]; a[4 + j] = ahi[j]; }
            }
            acc[f][0] = __builtin_amdgcn_mfma_f32_16x16x32_f16(a, b0, acc[f][0], 0, 0, 0);
            acc[f][1] = __builtin_amdgcn_mfma_f32_16x16x32_f16(a, b1, acc[f][1], 0, 0, 0);
        }
    }

    float bv0 = bias[lm];
    float bv1 = bias[16 + lm];
    float s0 = 0.f, s20 = 0.f, s1 = 0.f, s21 = 0.f;
    #pragma unroll
    for (int f = 0; f < 4; ++f) {
        #pragma unroll
        for (int r = 0; r < 4; ++r) {
            float v0 = acc[f][0][r] + bv0;
            float v1 = acc[f][1][r] + bv1;
            int p_loc = w * 64 + f * 16 + lg * 4 + r;
            s_y[p_loc * 32 + lm] = (_Float16)v0;
            s_y[p_loc * 32 + 16 + lm] = (_Float16)v1;
            s0 += v0; s20 += v0 * v0;
            s1 += v1; s21 += v1 * v1;
        }
    }
    s0 += __shfl_xor(s0, 16);  s0 += __shfl_xor(s0, 32);
    s1 += __shfl_xor(s1, 16);  s1 += __shfl_xor(s1, 32);
    s20 += __shfl_xor(s20, 16); s20 += __shfl_xor(s20, 32);
    s21 += __shfl_xor(s21, 16); s21 += __shfl_xor(s21, 32);
    if (l < 16) {
        atomicAdd(&s_red[lm], s0);
        atomicAdd(&s_red[16 + lm], s1);
        atomicAdd(&s_red[32 + lm], s20);
        atomicAdd(&s_red[48 + lm], s21);
    }
    __syncthreads();

    // coalesced Y store: 4 rows x 64 cols x 32 ch contiguous
    {
        _Float16* Yb = Yg + ((size_t)(n * 64 + row0) * 64) * 32;
        #pragma unroll
        for (int i = 0; i < 4; ++i) {
            int idx = t + 256 * i;
            *(half8*)&Yb[(size_t)idx * 8] = *(const half8*)&s_y[idx * 8];
        }
    }
    if (t < 64)
        partials[((size_t)n * 16 + blockIdx.x) * 64 + t] = s_red[t];
}

// ---------------------------------------------------------------------------
// conv2 FUSED v7: stages bn1(Yg)+relu tile from global (fused scale/shift at
// load, like conv3's coef path). No conv1 recompute, no weight staging.
// LDS 47.8 KB -> 3 blocks/CU. 512 thr, ROWS=8, pixel-major [660][36];
// grid (8,1,256).
// ---------------------------------------------------------------------------
__global__ __launch_bounds__(512, 6) void conv2_fused_kernel(
    const _Float16* __restrict__ Yg, const _Float16* __restrict__ ssh1,
    const _Float16* __restrict__ wt2, const float* __restrict__ c2bias,
    _Float16* __restrict__ out0, _Float16* __restrict__ out1,
    float* __restrict__ partials)
{
    constexpr int COUT = 32, MF = 4, NB = 2;
    constexpr int ROWS = 8;
    constexpr int TC = 66, NPIX = 10 * 66;         // 660
    constexpr int PS = 36;                          // pixel stride (halves)
    __shared__ __align__(16) _Float16 s_in[NPIX * PS];   // 47,520 B
    __shared__ float s_red[64];

    const int t = threadIdx.x;
    const int row0 = blockIdx.x * ROWS;
    const int n = blockIdx.z;
    const int w = t >> 6, l = t & 63;
    const int lm = l & 15, lg = l >> 4;

    if (t < 64) s_red[t] = 0.f;

    // ---- stage relu(bn1(Y)) tile: rows row0-1..row0+8, cols -1..64 ----
    {
        const int c8 = t & 3;                       // constant: 512 % 4 == 0
        half8 sc = *(const half8*)&ssh1[c8 * 8];
        half8 sh = *(const half8*)&ssh1[32 + c8 * 8];
        for (int idx = t; idx < NPIX * 4; idx += 512) {
            int p = idx >> 2;
            int py = p / 66, px = p - py * 66;
            int gy = row0 - 1 + py, gx = px - 1;
            half8 v;
            #pragma unroll
            for (int j = 0; j < 8; ++j) v[j] = (_Float16)0.f;
            if (gy >= 0 && gy < 64 && gx >= 0 && gx < 64) {
                half8 y = *(const half8*)&Yg[(((size_t)n * 64 + gy) * 64 + gx) * 32 + c8 * 8];
                #pragma unroll
                for (int j = 0; j < 8; ++j) {
                    _Float16 f = y[j] * sc[j] + sh[j];
                    v[j] = f > (_Float16)0.f ? f : (_Float16)0.f;
                }
            }
            half4* vp = (half4*)&v;
            *(half4*)&s_in[p * PS + c8 * 8] = vp[0];
            *(half4*)&s_in[p * PS + c8 * 8 + 4] = vp[1];
        }
    }
    __syncthreads();

    // ---- conv2 main compute: wave = output row (row0+w), columns f*16+lm ----
    int pA[MF];
    #pragma unroll
    for (int f = 0; f < MF; ++f)
        pA[f] = w * TC + f * 16 + lm;
    f32x4 zero4 = {0.f, 0.f, 0.f, 0.f};
    f32x4 acc[MF][NB];
    #pragma unroll
    for (int f = 0; f < MF; ++f)
        #pragma unroll
        for (int nb = 0; nb < NB; ++nb) acc[f][nb] = zero4;

    #pragma unroll
    for (int tap = 0; tap < 9; ++tap) {
        const int dy = tap / 3, dx = tap % 3;
        const int poff = dy * TC + dx;
        half8 b[NB];
        #pragma unroll
        for (int nb = 0; nb < NB; ++nb) {
            int col = nb * 16 + lm;
            b[nb] = *(const half8*)&wt2[((tap * 4 + lg) * 32 + col) * 8];
        }
        #pragma unroll
        for (int f = 0; f < MF; ++f) {
            int p = pA[f] + poff;
            half4 alo = *(const half4*)&s_in[p * PS + lg * 8];
            half4 ahi = *(const half4*)&s_in[p * PS + lg * 8 + 4];
            half8 a;
            #pragma unroll
            for (int j = 0; j < 4; ++j) { a[j] = alo[j]; a[4 + j] = ahi[j]; }
            #pragma unroll
            for (int nb = 0; nb < NB; ++nb)
                acc[f][nb] = __builtin_amdgcn_mfma_f32_16x16x32_f16(a, b[nb], acc[f][nb], 0, 0, 0);
        }
    }

    // ---- bias fold + stats (registers only) ----
    float bv[NB], s[NB], s2[NB];
    #pragma unroll
    for (int nb = 0; nb < NB; ++nb) {
        bv[nb] = c2bias[nb * 16 + lm];
        s[nb] = 0.f; s2[nb] = 0.f;
    }
    #pragma unroll
    for (int f = 0; f < MF; ++f) {
        #pragma unroll
        for (int nb = 0; nb < NB; ++nb) {
            #pragma unroll
            for (int r = 0; r < 4; ++r) {
                float v = acc[f][nb][r] + bv[nb];
                acc[f][nb][r] = v;
                s[nb] += v; s2[nb] += v * v;
            }
        }
    }
    #pragma unroll
    for (int nb = 0; nb < NB; ++nb) {
        s[nb] += __shfl_xor(s[nb], 16);  s[nb] += __shfl_xor(s[nb], 32);
        s2[nb] += __shfl_xor(s2[nb], 16); s2[nb] += __shfl_xor(s2[nb], 32);
    }
    if (l < 16) {
        #pragma unroll
        for (int nb = 0; nb < NB; ++nb) {
            atomicAdd(&s_red[nb * 16 + lm], s[nb]);
            atomicAdd(&s_red[32 + nb * 16 + lm], s2[nb]);
        }
    }

    // ---- pool: h-pool in lane -> pk rows -> vertical gather -> stores ----
    {
        __syncthreads();                    // all MFMA reads of s_in done
        _Float16* pk = s_in;                // [8 rows][32 xp][32 ch] min, +8192 max
        #pragma unroll
        for (int nb = 0; nb < NB; ++nb) {
            #pragma unroll
            for (int f = 0; f < MF; ++f) {
                float v0 = acc[f][nb][0], v1 = acc[f][nb][1];
                float v2 = acc[f][nb][2], v3 = acc[f][nb][3];
                int xp0 = f * 8 + lg * 2;
                int o0 = (w * 32 + xp0) * COUT + nb * 16 + lm;
                int o1 = (w * 32 + xp0 + 1) * COUT + nb * 16 + lm;
                pk[o0] = (_Float16)fminf(v0, v1);
                pk[8192 + o0] = (_Float16)fmaxf(v0, v1);
                pk[o1] = (_Float16)fminf(v2, v3);
                pk[8192 + o1] = (_Float16)fmaxf(v2, v3);
            }
        }
        __syncthreads();
        // vertical gather: 4 pooled rows x 32 xp x 4 c8 = 512 threads
        int hp_row = t >> 7, rem = t & 127;
        int xp = rem >> 2, c8 = rem & 3;
        half8 mnA = *(const half8*)&pk[((2 * hp_row) * 32 + xp) * COUT + c8 * 8];
        half8 mnB = *(const half8*)&pk[((2 * hp_row + 1) * 32 + xp) * COUT + c8 * 8];
        half8 mxA = *(const half8*)&pk[8192 + ((2 * hp_row) * 32 + xp) * COUT + c8 * 8];
        half8 mxB = *(const half8*)&pk[8192 + ((2 * hp_row + 1) * 32 + xp) * COUT + c8 * 8];
        half8 mn, mx;
        #pragma unroll
        for (int j = 0; j < 8; ++j) {
            mn[j] = mnA[j] < mnB[j] ? mnA[j] : mnB[j];
            mx[j] = mxA[j] > mxB[j] ? mxA[j] : mxB[j];
        }
        size_t ob = (((size_t)n * 32 + (row0 >> 1) + hp_row) * 32 + xp) * COUT + c8 * 8;
        *(half8*)&out0[ob] = mn;
        *(half8*)&out1[ob] = mx;
    }

    __syncthreads();
    if (t < 64) {
        size_t bid = (size_t)n * gridDim.x + blockIdx.x;
        partials[bid * 64 + t] = s_red[t];
    }
}

// ---------------------------------------------------------------------------
// Implicit-GEMM 3x3 conv via MFMA (single-pass staging). Used for conv3/conv4.
// ---------------------------------------------------------------------------
template<int BLOCK, int W, int CIN, int COUT, int MF, int NB,
         bool MMIN, bool POOL>
__global__ __launch_bounds__(BLOCK, (BLOCK == 512 ? 4 : 3)) void conv_mfma_kernel(
    const _Float16* __restrict__ in0, const _Float16* __restrict__ in1,
    const _Float16* __restrict__ coef, const _Float16* __restrict__ wt,
    const float* __restrict__ bias,
    _Float16* __restrict__ out0, _Float16* __restrict__ out1,
    float* __restrict__ partials)
{
    constexpr int H = W;
    constexpr int NWAVE = BLOCK / 64;
    constexpr int SPW = MF * 16;
    constexpr int ROWS = NWAVE * SPW / W;
    constexpr int TR = ROWS + 2;
    constexpr int TC = W + 2;
    constexpr int NPIX = TR * TC;
    constexpr int NCH = CIN / 32;
    constexpr int C8N = CIN / 8;
    constexpr int KC = 288;
    constexpr int COUTB = NB * 16;
    __shared__ __align__(16) _Float16 s_in[NPIX * CIN];
    __shared__ float s_red[2 * COUTB];

    const int t = threadIdx.x;
    const int row0 = blockIdx.x * ROWS;
    const int n = blockIdx.z;

    const int w = t >> 6, l = t & 63;
    const int lm = l & 15, lg = l >> 4;
    int pA[MF];
    #pragma unroll
    for (int f = 0; f < MF; ++f) {
        int m = w * SPW + f * 16 + lm;
        pA[f] = (m / W) * TC + (m % W);
    }
    f32x4 zero4 = {0.f, 0.f, 0.f, 0.f};
    f32x4 acc[MF][NB];
    #pragma unroll
    for (int f = 0; f < MF; ++f)
        #pragma unroll
        for (int nb = 0; nb < NB; ++nb) acc[f][nb] = zero4;
    if (t < 2 * COUTB) s_red[t] = 0.f;

    for (int idx = t; idx < NPIX * C8N; idx += BLOCK) {
        int c8 = idx % C8N;
        int p = idx / C8N;
        int col = p % TC, r = p / TC;
        int gy = row0 + r - 1, gx = col - 1;
        half8 v;
        #pragma unroll
        for (int j = 0; j < 8; ++j) v[j] = (_Float16)0.f;
        if (gy >= 0 && gy < H && gx >= 0 && gx < W) {
            size_t gidx = (((size_t)n * H + gy) * W + gx) * CIN + c8 * 8;
            if (MMIN) {
                half8 mn = *(const half8*)&in0[gidx];
                half8 mx = *(const half8*)&in1[gidx];
                half8 sa = *(const half8*)&coef[c8 * 8];
                half8 sb = *(const half8*)&coef[CIN + c8 * 8];
                half8 sh = *(const half8*)&coef[2 * CIN + c8 * 8];
                #pragma unroll
                for (int j = 0; j < 8; ++j) {
                    _Float16 f = mx[j] * sa[j] + mn[j] * sb[j] + sh[j];
                    v[j] = f > (_Float16)0.f ? f : (_Float16)0.f;
                }
            } else {
                v = *(const half8*)&in0[gidx];
                if (coef) {
                    half8 sc = *(const half8*)&coef[c8 * 8];
                    half8 sh = *(const half8*)&coef[CIN + c8 * 8];
                    #pragma unroll
                    for (int j = 0; j < 8; ++j) {
                        _Float16 f = v[j] * sc[j] + sh[j];
                        v[j] = f > (_Float16)0.f ? f : (_Float16)0.f;
                    }
                }
            }
        }
        *(half8*)&s_in[(c8 * NPIX + p) * 8] = v;
    }
    __syncthreads();

    #pragma unroll
    for (int tap = 0; tap < 9; ++tap) {
        const int dy = tap / 3, dx = tap % 3;
        const int poff = dy * TC + dx;
        #pragma unroll
        for (int cc = 0; cc < NCH; ++cc) {
            half8 b[NB];
            #pragma unroll
            for (int nb = 0; nb < NB; ++nb) {
                int cog = nb * 16 + lm;
                int gg = cog >> 5, col = cog & 31;
                const _Float16* wp = wt + (size_t)(gg * NCH + cc) * KC * 32;
                b[nb] = *(const half8*)&wp[((tap * 4 + lg) * 32 + col) * 8];
            }
            #pragma unroll
            for (int f = 0; f < MF; ++f) {
                half8 a = *(const half8*)&s_in[((cc * 4 + lg) * NPIX + pA[f] + poff) * 8];
                #pragma unroll
                for (int nb = 0; nb < NB; ++nb)
                    acc[f][nb] = __builtin_amdgcn_mfma_f32_16x16x32_f16(a, b[nb], acc[f][nb], 0, 0, 0);
            }
        }
    }

    float bv[NB], s[NB], s2[NB];
    #pragma unroll
    for (int nb = 0; nb < NB; ++nb) {
        bv[nb] = bias[nb * 16 + lm];
        s[nb] = 0.f; s2[nb] = 0.f;
    }
    #pragma unroll
    for (int f = 0; f < MF; ++f) {
        #pragma unroll
        for (int r = 0; r < 4; ++r) {
            int m = w * SPW + f * 16 + lg * 4 + r;
            int yy = row0 + m / W, xo = m % W;
            size_t base = (((size_t)n * H + yy) * W + xo) * COUT;
            #pragma unroll
            for (int nb = 0; nb < NB; ++nb) {
                float v = acc[f][nb][r] + bv[nb];
                if (!POOL) out0[base + nb * 16 + lm] = (_Float16)v;
                s[nb] += v; s2[nb] += v * v;
            }
        }
    }
    #pragma unroll
    for (int nb = 0; nb < NB; ++nb) {
        s[nb] += __shfl_xor(s[nb], 16);  s[nb] += __shfl_xor(s[nb], 32);
        s2[nb] += __shfl_xor(s2[nb], 16); s2[nb] += __shfl_xor(s2[nb], 32);
    }
    if (l < 16) {
        #pragma unroll
        for (int nb = 0; nb < NB; ++nb) {
            atomicAdd(&s_red[nb * 16 + lm], s[nb]);
            atomicAdd(&s_red[COUTB + nb * 16 + lm], s2[nb]);
        }
    }

    if (POOL) {
        constexpr int FH = MF / 2;
        constexpr int PPIX = (ROWS / 2) * (W / 2);
        static_assert(2 * PPIX * COUT <= NPIX * CIN, "pool pack fits in s_in");
        __syncthreads();
        _Float16* pk = s_in;
        #pragma unroll
        for (int nb = 0; nb < NB; ++nb) {
            #pragma unroll
            for (int f = 0; f < FH; ++f) {
                #pragma unroll
                for (int rp = 0; rp < 2; ++rp) {
                    float a0 = acc[f][nb][2 * rp] + bv[nb];
                    float a1 = acc[f][nb][2 * rp + 1] + bv[nb];
                    float a2 = acc[f + FH][nb][2 * rp] + bv[nb];
                    float a3 = acc[f + FH][nb][2 * rp + 1] + bv[nb];
                    float mn = fminf(fminf(a0, a1), fminf(a2, a3));
                    float mx = fmaxf(fmaxf(a0, a1), fmaxf(a2, a3));
                    int xp = f * 8 + lg * 2 + rp;
                    int o = (w * (W / 2) + xp) * COUT + nb * 16 + lm;
                    pk[o] = (_Float16)mn;
                    pk[PPIX * COUT + o] = (_Float16)mx;
                }
            }
        }
        __syncthreads();
        size_t gb = (((size_t)n * (H / 2) + (row0 >> 1)) * (W / 2)) * COUT;
        for (int idx = t; idx < PPIX * COUT / 8; idx += BLOCK) {
            *(half8*)&out0[gb + (size_t)idx * 8] = *(const half8*)&pk[idx * 8];
            *(half8*)&out1[gb + (size_t)idx * 8] = *(const half8*)&pk[(PPIX * COUT + idx * 8)];
        }
    }

    __syncthreads();
    if (t < 2 * COUTB) {
        size_t bid = (size_t)n * gridDim.x + blockIdx.x;
        partials[bid * 2 * COUTB + t] = s_red[t];
    }
}

// ---------------------------------------------------------------------------
// Reduce per-block partials -> BN coefficients. Record = [sum C | sumsq C].
// ---------------------------------------------------------------------------
__global__ __launch_bounds__(256) void bn_finalize_kernel(
    const float* __restrict__ partials, int nx, float inv_count,
    const float* __restrict__ gamma, const float* __restrict__ beta,
    float* __restrict__ ss, _Float16* __restrict__ ssh,
    _Float16* __restrict__ sab, int COUT)
{
    const int c = blockIdx.x;
    const int t = threadIdx.x;
    float sum = 0.f, sq = 0.f;
    int total = 256 * nx;
    for (int e = t; e < total; e += 256) {
        size_t off = (size_t)e * 2 * COUT;
        sum += partials[off + c];
        sq  += partials[off + COUT + c];
    }
    #pragma unroll
    for (int off = 32; off > 0; off >>= 1) {
        sum += __shfl_xor(sum, off);
        sq  += __shfl_xor(sq, off);
    }
    __shared__ float rs[4], rq[4];
    if ((t & 63) == 0) { rs[t >> 6] = sum; rq[t >> 6] = sq; }
    __syncthreads();
    if (t == 0) {
        sum = rs[0] + rs[1] + rs[2] + rs[3];
        sq  = rq[0] + rq[1] + rq[2] + rq[3];
        float mean = sum * inv_count;
        float var = sq * inv_count - mean * mean;
        float scale = gamma[c] * rsqrtf(var + 1e-5f);
        float shift = beta[c] - mean * scale;
        ss[c] = scale;
        ss[COUT + c] = shift;
        if (ssh) {
            ssh[c] = (_Float16)scale;
            ssh[COUT + c] = (_Float16)shift;
        }
        if (sab) {
            sab[c] = (_Float16)(scale > 0.f ? scale : 0.f);
            sab[COUT + c] = (_Float16)(scale > 0.f ? 0.f : scale);
            sab[2 * COUT + c] = (_Float16)shift;
        }
    }
}

// ---------------------------------------------------------------------------
// fc1 MFMA GEMM (K-split): A = relu(bn4(pooled minmax pair)) on the fly.
// ---------------------------------------------------------------------------
__global__ __launch_bounds__(256) void fc1_mfma_kernel(
    const _Float16* __restrict__ Amin, const _Float16* __restrict__ Amax,
    const _Float16* __restrict__ sab, const _Float16* __restrict__ Bw,
    float* __restrict__ hp)
{
    __shared__ __align__(16) _Float16 As[64][72];
    __shared__ __align__(16) _Float16 Bs[128][72];
    const int t = threadIdx.x;
    const int mt = blockIdx.x;
    const int kc = blockIdx.y;
    const int w = t >> 6, l = t & 63;
    const int lm = l & 15, lg = l >> 4;

    f32x4 zero4 = {0.f, 0.f, 0.f, 0.f};
    f32x4 acc[8];
    #pragma unroll
    for (int nb = 0; nb < 8; ++nb) acc[nb] = zero4;

    const size_t a_base = (size_t)(mt * 64) * 16384 + (size_t)kc * 512;
    const size_t b_base = (size_t)kc * 512;

    for (int p = 0; p < 8; ++p) {
        __syncthreads();
        #pragma unroll
        for (int i = 0; i < 2; ++i) {
            int idx = t + 256 * i;
            int r = idx >> 3, c8 = idx & 7;
            size_t off = a_base + (size_t)r * 16384 + p * 64 + c8 * 8;
            half8 mn = *(const half8*)&Amin[off];
            half8 mx = *(const half8*)&Amax[off];
            half8 sa = *(const half8*)&sab[c8 * 8];
            half8 sb = *(const half8*)&sab[64 + c8 * 8];
            half8 sh = *(const half8*)&sab[128 + c8 * 8];
            half8 v;
            #pragma unroll
            for (int j = 0; j < 8; ++j) {
                _Float16 f = mx[j] * sa[j] + mn[j] * sb[j] + sh[j];
                v[j] = f > (_Float16)0.f ? f : (_Float16)0.f;
            }
            *(half8*)&As[r][c8 * 8] = v;
        }
        #pragma unroll
        for (int i = 0; i < 4; ++i) {
            int idx = t + 256 * i;
            int r = idx >> 3, c8 = idx & 7;
            *(half8*)&Bs[r][c8 * 8] =
                *(const half8*)&Bw[b_base + (size_t)r * 16384 + p * 64 + c8 * 8];
        }
        __syncthreads();
        #pragma unroll
        for (int ks = 0; ks < 64; ks += 32) {
            half8 a = *(const half8*)&As[w * 16 + lm][ks + lg * 8];
            #pragma unroll
            for (int nb = 0; nb < 8; ++nb) {
                half8 b = *(const half8*)&Bs[nb * 16 + lm][ks + lg * 8];
                acc[nb] = __builtin_amdgcn_mfma_f32_16x16x32_f16(a, b, acc[nb], 0, 0, 0);
            }
        }
    }
    #pragma unroll
    for (int nb = 0; nb < 8; ++nb) {
        #pragma unroll
        for (int r = 0; r < 4; ++r) {
            int row = mt * 64 + w * 16 + lg * 4 + r;
            hp[((size_t)kc * 256 + row) * 128 + nb * 16 + lm] = acc[nb][r];
        }
    }
}

// ---------------------------------------------------------------------------
// fc1 reduce + relu + fc2 + quantum circuit + head, one block per batch n.
// 128 threads: fc phase uses all; quantum runs on wave 0 (t<64).
// ---------------------------------------------------------------------------
__global__ __launch_bounds__(128) void fcq_kernel(
    const float* __restrict__ hp, const float* __restrict__ f1b,
    const float* __restrict__ f2w, const float* __restrict__ f2b,
    const float* __restrict__ rotm, const unsigned short* __restrict__ perm,
    const float* __restrict__ head_w, const float* __restrict__ head_b,
    float* __restrict__ outp)
{
    __shared__ float lds[2048];
    __shared__ float hl[128];
    __shared__ float xql[10];
    const int n = blockIdx.x;
    const int t = threadIdx.x;

    // ---- fc1 reduce + bias + relu ----
    {
        float s = f1b[t];
        #pragma unroll
        for (int kc = 0; kc < 32; ++kc) s += hp[((size_t)kc * 256 + n) * 128 + t];
        hl[t] = fmaxf(0.f, s);
    }
    __syncthreads();
    // ---- fc2 ----
    if (t < 10) {
        float o = f2b[t];
        #pragma unroll 4
        for (int k = 0; k < 128; ++k) o += f2w[t * 128 + k] * hl[k];
        xql[t] = o;
    }
    __syncthreads();
    if (t >= 64) return;     // wave 1 exits; quantum runs on wave 0

    const int l = t;
    float ar[16], ai[16];
    #pragma unroll
    for (int r = 0; r < 16; ++r) { ar[r] = 0.f; ai[r] = 0.f; }
    if (l == 0) ar[0] = 1.f;

    #pragma unroll
    for (int w = 0; w < 10; ++w) {
        float th = 0.5f * PI_F * xql[w];
        float c = cosf(th), s = sinf(th);
        const int k = 9 - w;
        if (k >= 6) {
            const int b = k - 6;
            #pragma unroll
            for (int r = 0; r < 16; ++r) {
                if (!(r & (1 << b))) {
                    int r1 = r | (1 << b);
                    float a0 = ar[r], a1 = ar[r1];
                    ar[r]  = c * a0 - s * a1;
                    ar[r1] = s * a0 + c * a1;
                }
            }
        } else {
            float ss = ((l >> k) & 1) ? s : -s;
            #pragma unroll
            for (int r = 0; r < 16; ++r) {
                float p = __shfl_xor(ar[r], 1 << k);
                ar[r] = c * ar[r] + ss * p;
            }
        }
    }

    #pragma unroll 1
    for (int layer = 0; layer < 6; ++layer) {
        #pragma unroll
        for (int w = 0; w < 10; ++w) {
            const float* m = rotm + (layer * 10 + w) * 8;
            float m00r = m[0], m00i = m[1], m01r = m[2], m01i = m[3];
            float m10r = m[4], m10i = m[5], m11r = m[6], m11i = m[7];
            const int k = 9 - w;
            if (k >= 6) {
                const int b = k - 6;
                #pragma unroll
                for (int r = 0; r < 16; ++r) {
                    if (!(r & (1 << b))) {
                        int r1 = r | (1 << b);
                        float a0r = ar[r], a0i = ai[r];
                        float a1r = ar[r1], a1i = ai[r1];
                        ar[r]  = m00r * a0r - m00i * a0i + m01r * a1r - m01i * a1i;
                        ai[r]  = m00r * a0i + m00i * a0r + m01r * a1i + m01i * a1r;
                        ar[r1] = m10r * a0r - m10i * a0i + m11r * a1r - m11i * a1i;
                        ai[r1] = m10r * a0i + m10i * a0r + m11r * a1i + m11i * a1r;
                    }
                }
            } else {
                int bit = (l >> k) & 1;
                float mAr = bit ? m11r : m00r, mAi = bit ? m11i : m00i;
                float mBr = bit ? m10r : m01r, mBi = bit ? m10i : m01i;
                #pragma unroll
                for (int r = 0; r < 16; ++r) {
                    float pr = __shfl_xor(ar[r], 1 << k);
                    float pi = __shfl_xor(ai[r], 1 << k);
                    float mr = ar[r], mi = ai[r];
                    ar[r] = mAr * mr - mAi * mi + mBr * pr - mBi * pi;
                    ai[r] = mAr * mi + mAi * mr + mBr * pi + mBi * pr;
                }
            }
        }
        #pragma unroll
        for (int r = 0; r < 16; ++r) {
            lds[(r << 6) | l] = ar[r];
            lds[1024 + ((r << 6) | l)] = ai[r];
        }
        __syncthreads();
        const unsigned short* pt = perm + layer * 1024;
        #pragma unroll
        for (int r = 0; r < 16; ++r) {
            int ji = pt[(r << 6) | l];
            ar[r] = lds[ji];
            ai[r] = lds[1024 + ji];
        }
        __syncthreads();
    }

    float S = 0.f, T0 = 0.f, T1 = 0.f, T2 = 0.f, T3 = 0.f;
    #pragma unroll
    for (int r = 0; r < 16; ++r) {
        float pr = ar[r] * ar[r] + ai[r] * ai[r];
        S += pr;
        T0 += (r & 1) ? -pr : pr;
        T1 += (r & 2) ? -pr : pr;
        T2 += (r & 4) ? -pr : pr;
        T3 += (r & 8) ? -pr : pr;
    }
    float pk[10];
    pk[0] = T3; pk[1] = T2; pk[2] = T1; pk[3] = T0;
    #pragma unroll
    for (int w = 4; w < 10; ++w)
        pk[w] = ((l >> (9 - w)) & 1) ? -S : S;
    #pragma unroll
    for (int w = 0; w < 10; ++w) {
        #pragma unroll
        for (int off = 1; off < 64; off <<= 1)
            pk[w] += __shfl_xor(pk[w], off);
    }
    if (l < 10) {
        float o = head_b[l];
        #pragma unroll
        for (int kk = 0; kk < 10; ++kk) o += pk[kk] * head_w[l * 10 + kk];
        outp[n * 10 + l] = o;
    }
}

// ---------------------------------------------------------------------------
extern "C" void kernel_launch(void* const* d_in, const int* in_sizes, int n_in,
                              void* d_out, int out_size, void* d_ws, size_t ws_size,
                              hipStream_t stream)
{
    const float* x   = (const float*)d_in[0];
    const float* c1w = (const float*)d_in[1];  const float* c1b = (const float*)d_in[2];
    const float* g1  = (const float*)d_in[3];  const float* b1  = (const float*)d_in[4];
    const float* c2w = (const float*)d_in[5];  const float* c2b = (const float*)d_in[6];
    const float* g2  = (const float*)d_in[7];  const float* b2  = (const float*)d_in[8];
    const float* c3w = (const float*)d_in[9];  const float* c3b = (const float*)d_in[10];
    const float* g3  = (const float*)d_in[11]; const float* b3  = (const float*)d_in[12];
    const float* c4w = (const float*)d_in[13]; const float* c4b = (const float*)d_in[14];
    const float* g4  = (const float*)d_in[15]; const float* b4  = (const float*)d_in[16];
    const float* f1w = (const float*)d_in[17]; const float* f1b = (const float*)d_in[18];
    const float* f2w = (const float*)d_in[19]; const float* f2b = (const float*)d_in[20];
    const float* qw  = (const float*)d_in[21];
    const float* hw  = (const float*)d_in[22]; const float* hb  = (const float*)d_in[23];

    float* ws = (float*)d_ws;
    _Float16* H0 = (_Float16*)ws;              // 33,554,432 halves (67 MB)
    _Float16* H1 = H0 + 33554432;              // 33,554,432 halves (67 MB)
    float* part = ws + 33554432;               // 524,288
    float* ss1  = part + 524288;               // 64
    float* ss2  = ss1 + 64;                    // 64
    float* ss3  = ss2 + 64;                    // 128
    float* ss4  = ss3 + 128;                   // 128
    float* hp   = ss4 + 128;                   // 1,048,576
    float* rotm = hp + 1048576;                // 480
    unsigned short* perm16 = (unsigned short*)(rotm + 480);   // 6,144 u16
    _Float16* ssh1 = (_Float16*)(perm16 + 6144);   // 64 halves
    _Float16* ssh3 = ssh1 + 64;                // 128
    _Float16* sab2 = ssh3 + 128;               // 96
    _Float16* sab4 = sab2 + 96;                // 192
    _Float16* wt2  = sab4 + 192;               // 9,216
    _Float16* wt3  = wt2 + 9216;               // 18,432
    _Float16* wt4  = wt3 + 18432;              // 36,864
    _Float16* w1m  = wt4 + 36864;              // 2,048
    _Float16* w1t  = w1m + 2048;               // 2,097,152
    _Float16* X4P  = w1t + 2097152;            // 4,874,240 (256*70*68*4, 9.75 MB)

    // overlays (sequential lifetimes):
    //  Yg (conv1+bias fp16, 256x64x64x32 = 33.5M halves) = H0; dead once conv2
    //  completes; conv3 then writes its output into H0.
    _Float16* Yg    = H0;
    _Float16* minT2 = H1;                      // (256,32,32,32)
    _Float16* maxT2 = H1 + 8388608;
    _Float16* minT4 = H1;                      // (256,16,16,64)
    _Float16* maxT4 = H1 + 4194304;

    // unified one-time prep
    prep_kernel<<<3153, 256, 0, stream>>>(x, X4P, c1w, c2w, c3w, c4w,
                                          w1m, wt2, wt3, wt4, f1w, w1t,
                                          qw, rotm, perm16);

    // conv1: Y = fp16(conv1+bias) -> Yg (H0) + BN1 stats
    conv1_stats_kernel<<<dim3(16, 1, 256), 256, 0, stream>>>(
        X4P, w1m, c1b, Yg, part);
    bn_finalize_kernel<<<32, 256, 0, stream>>>(part, 16, 1.f / 1048576.f,
                                               g1, b1, ss1, ssh1, nullptr, 32);

    // conv2 FUSED v7 (stages relu(bn1(Yg)) from global): -> minT2/maxT2 + stats
    conv2_fused_kernel<<<dim3(8, 1, 256), 512, 0, stream>>>(
        Yg, ssh1, wt2, c2b, minT2, maxT2, part);
    bn_finalize_kernel<<<32, 256, 0, stream>>>(part, 8, 1.f / 1048576.f,
                                               g2, b2, ss2, nullptr, sab2, 32);

    // conv3 (512thr, 64 cout/wave, minmax input): relu(bn2(pool1)) -> H0
    conv_mfma_kernel<512, 32, 32, 64, 4, 4, true, false>
        <<<dim3(2, 1, 256), 512, 0, stream>>>(
        minT2, maxT2, sab2, wt3, c3b, H0, nullptr, part);
    bn_finalize_kernel<<<64, 256, 0, stream>>>(part, 2, 1.f / 262144.f,
                                               g3, b3, ss3, ssh3, nullptr, 64);

    // conv4 (512thr, single-pass CIN=64 staging, packed pooled stores)
    conv_mfma_kernel<512, 32, 64, 64, 4, 4, false, true>
        <<<dim3(2, 1, 256), 512, 0, stream>>>(
        H0, nullptr, ssh3, wt4, c4b, minT4, maxT4, part);
    bn_finalize_kernel<<<64, 256, 0, stream>>>(part, 2, 1.f / 262144.f,
                                               g4, b4, ss4, nullptr, sab4, 64);

    // fc1: MFMA GEMM with on-the-fly relu(bn4(pool2))
    fc1_mfma_kernel<<<dim3(4, 32), 256, 0, stream>>>(minT4, maxT4, sab4, w1t, hp);

    // fc1-reduce + fc2 + quantum circuit + head -> out (256,10)
    fcq_kernel<<<256, 128, 0, stream>>>(hp, f1b, f2w, f2b,
                                        rotm, perm16, hw, hb, (float*)d_out);
}

// Round 23
// 184.365 us; speedup vs baseline: 1.0569x; 1.0569x over previous
//
#include <hip/hip_runtime.h>
#include <math.h>

#define PI_F 3.14159265358979323846f

typedef __attribute__((ext_vector_type(8))) _Float16 half8;
typedef __attribute__((ext_vector_type(4))) _Float16 half4;
typedef __attribute__((ext_vector_type(4))) float f32x4;

// ---------------------------------------------------------------------------
// Unified prep kernel, grid 3153x256:
//  [0,2380)    x (256,3,64,64) fp32 -> X4P (256,70,68,4) fp16, zero border
//  [2380,2640) conv weight transforms (channel-blocked fp16)
//  [2640,3152) fc1 weight transform (NCHW-k -> NHWC-k fp16)
//  [3152]      quantum prep: 60 Rot matrices + 6x1024 u16 perm table
// ---------------------------------------------------------------------------
__global__ __launch_bounds__(256) void prep_kernel(
    const float* __restrict__ x, _Float16* __restrict__ X4P,
    const float* __restrict__ w1, const float* __restrict__ w2,
    const float* __restrict__ w3, const float* __restrict__ w4,
    _Float16* __restrict__ t1, _Float16* __restrict__ t2,
    _Float16* __restrict__ t3, _Float16* __restrict__ t4,
    const float* __restrict__ f1w, _Float16* __restrict__ w1t,
    const float* __restrict__ qw, float* __restrict__ rotm,
    unsigned short* __restrict__ perm)
{
    const int b = blockIdx.x;
    const int t = threadIdx.x;
    if (b < 2380) {
        int pp = (b * 256 + t) * 2;          // 2 pixels per thread
        half8 o;
        #pragma unroll
        for (int j = 0; j < 2; ++j) {
            int p = pp + j;
            int n = p / 4760;
            int rem = p - n * 4760;
            int yp = rem / 68, xp = rem - (rem / 68) * 68;
            int gy = yp - 2, gx = xp - 2;
            float v0 = 0.f, v1 = 0.f, v2 = 0.f;
            if (gy >= 0 && gy < 64 && gx >= 0 && gx < 64) {
                const float* xb = x + (size_t)n * 12288 + gy * 64 + gx;
                v0 = xb[0]; v1 = xb[4096]; v2 = xb[8192];
            }
            o[j * 4 + 0] = (_Float16)v0;
            o[j * 4 + 1] = (_Float16)v1;
            o[j * 4 + 2] = (_Float16)v2;
            o[j * 4 + 3] = (_Float16)0.f;
        }
        *(half8*)&X4P[(size_t)pp * 4] = o;
    } else if (b < 2640) {
        int idx = (b - 2380) * 256 + t;
        if (idx < 9216) {               // conv2: K=288, 1 group
            int j = idx & 7, co = (idx >> 3) & 31, k8 = idx >> 8;
            int k = k8 * 8 + j, tap = k >> 5, ci = k & 31;
            t2[idx] = (_Float16)w2[(size_t)(co * 32 + ci) * 9 + tap];
        } else if (idx < 27648) {       // conv3: 2 cout groups
            int e = idx - 9216;
            int j = e & 7, co = (e >> 3) & 31, r = e >> 8;
            int k8 = r % 36, gg = r / 36;
            int k = k8 * 8 + j, tap = k >> 5, ci = k & 31;
            t3[e] = (_Float16)w3[(size_t)((gg * 32 + co) * 32 + ci) * 9 + tap];
        } else if (idx < 64512) {       // conv4: 2 cout groups x 2 ci-chunks
            int e = idx - 27648;
            int j = e & 7, co = (e >> 3) & 31, r = e >> 8;
            int k8 = r % 36, gc = r / 36;
            int g = gc >> 1, cc = gc & 1;
            int kl = k8 * 8 + j, tap = kl >> 5, ci = cc * 32 + (kl & 31);
            t4[e] = (_Float16)w4[(size_t)((g * 32 + co) * 64 + ci) * 9 + tap];
        } else if (idx < 66560) {       // conv1: K=64 padded
            int e = idx - 64512;
            int j = e & 7, co = (e >> 3) & 31, k8 = e >> 8;
            int k = k8 * 8 + j, tap = k >> 2, ci = k & 3;
            t1[e] = (_Float16)((tap < 9 && ci < 3) ? w1[(size_t)(co * 3 + ci) * 9 + tap] : 0.f);
        }
    } else if (b < 3152) {
        __shared__ float lds[64][65];
        int b2 = b - 2640;
        const int yx0 = (b2 & 3) * 64;
        const int j = b2 >> 2;
        #pragma unroll
        for (int i = 0; i < 16; ++i) {
            int idx = t + 256 * i;
            int c = idx >> 6, yxl = idx & 63;
            lds[c][yxl] = f1w[(size_t)j * 16384 + c * 256 + yx0 + yxl];
        }
        __syncthreads();
        #pragma unroll
        for (int i = 0; i < 2; ++i) {
            int idx = t + 256 * i;
            int yxl = idx >> 3, c8 = idx & 7;
            half8 h;
            #pragma unroll
            for (int jj = 0; jj < 8; ++jj)
                h[jj] = (_Float16)lds[c8 * 8 + jj][yxl];
            *(half8*)&w1t[(size_t)j * 16384 + (size_t)(yx0 + yxl) * 64 + c8 * 8] = h;
        }
    } else {
        if (t < 60) {
            float phi = qw[t * 3], th = qw[t * 3 + 1], om = qw[t * 3 + 2];
            float c = cosf(0.5f * th), s = sinf(0.5f * th);
            float apo = 0.5f * (phi + om), amo = 0.5f * (phi - om);
            float cpo = cosf(apo), spo = sinf(apo);
            float cmo = cosf(amo), smo = sinf(amo);
            rotm[t * 8 + 0] = cpo * c;  rotm[t * 8 + 1] = -spo * c;
            rotm[t * 8 + 2] = -cmo * s; rotm[t * 8 + 3] = -smo * s;
            rotm[t * 8 + 4] = cmo * s;  rotm[t * 8 + 5] = -smo * s;
            rotm[t * 8 + 6] = cpo * c;  rotm[t * 8 + 7] = spo * c;
        }
        for (int e = t; e < 6144; e += 256) {
            int layer = e >> 10, i = e & 1023;
            int r = layer % 9 + 1;
            int jdx = i;
            for (int w = 9; w >= 0; --w) {
                int tt = (w + r) % 10;
                int pc = 9 - w, pt_ = 9 - tt;
                jdx ^= ((jdx >> pc) & 1) << pt_;
            }
            perm[e] = (unsigned short)jdx;
        }
    }
}

// ---------------------------------------------------------------------------
// conv1: conv1 via MFMA from X4P -> Yg = fp16(conv1+bias) NHWC (256,64,64,32)
// + BN1 partials. Y packed through LDS for coalesced half8 stores.
// ---------------------------------------------------------------------------
__global__ __launch_bounds__(256) void conv1_stats_kernel(
    const _Float16* __restrict__ X4P, const _Float16* __restrict__ w1m,
    const float* __restrict__ bias, _Float16* __restrict__ Yg,
    float* __restrict__ partials)
{
    constexpr int TC = 66, TR = 6;
    constexpr int NPIX = (TR + 1) * TC;     // 462
    __shared__ __align__(16) _Float16 s_in[NPIX * 4];
    __shared__ __align__(16) _Float16 s_w[2048];
    __shared__ __align__(16) _Float16 s_y[256 * 32];   // 16 KB
    __shared__ float s_red[64];

    const int t = threadIdx.x;
    const int row0 = blockIdx.x * 4;
    const int n = blockIdx.z;

    *(half8*)&s_w[t * 8] = *(const half8*)&w1m[t * 8];

    for (int p = t; p < NPIX; p += 256) {
        int col = p % TC, r = p / TC;
        uint2 u = make_uint2(0u, 0u);
        if (r < TR) {
            size_t pb = ((size_t)(n * 70 + row0 + r + 1) * 68 + col + 1) * 4;
            u = *(const uint2*)&X4P[pb];
        }
        *(uint2*)&s_in[p * 4] = u;
    }
    if (t < 64) s_red[t] = 0.f;
    __syncthreads();

    const int w = t >> 6, l = t & 63;
    const int lm = l & 15, lg = l >> 4;
    int pA[4];
    #pragma unroll
    for (int f = 0; f < 4; ++f) {
        int m = w * 64 + f * 16 + lm;
        pA[f] = (m >> 6) * TC + (m & 63);
    }
    f32x4 zero4 = {0.f, 0.f, 0.f, 0.f};
    f32x4 acc[4][2];
    #pragma unroll
    for (int f = 0; f < 4; ++f) { acc[f][0] = zero4; acc[f][1] = zero4; }

    {
        const int t0 = lg * 2;
        const int off0 = (t0 / 3) * TC + (t0 % 3);
        const int off1 = ((t0 + 1) / 3) * TC + ((t0 + 1) % 3);
        half8 b0 = *(const half8*)&s_w[(lg * 32 + lm) * 8];
        half8 b1 = *(const half8*)&s_w[(lg * 32 + 16 + lm) * 8];
        #pragma unroll
        for (int f = 0; f < 4; ++f) {
            half4 alo = *(const half4*)&s_in[(pA[f] + off0) * 4];
            half4 ahi = *(const half4*)&s_in[(pA[f] + off1) * 4];
            half8 a;
            #pragma unroll
            for (int j = 0; j < 4; ++j) { a[j] = alo[j]; a[4 + j] = ahi[j]; }
            acc[f][0] = __builtin_amdgcn_mfma_f32_16x16x32_f16(a, b0, acc[f][0], 0, 0, 0);
            acc[f][1] = __builtin_amdgcn_mfma_f32_16x16x32_f16(a, b1, acc[f][1], 0, 0, 0);
        }
    }
    {
        half8 b0 = *(const half8*)&s_w[((4 + lg) * 32 + lm) * 8];
        half8 b1 = *(const half8*)&s_w[((4 + lg) * 32 + 16 + lm) * 8];
        #pragma unroll
        for (int f = 0; f < 4; ++f) {
            half8 a;
            #pragma unroll
            for (int j = 0; j < 8; ++j) a[j] = (_Float16)0.f;
            if (lg == 0) {
                half4 alo = *(const half4*)&s_in[(pA[f] + 134) * 4];
                half4 ahi = *(const half4*)&s_in[(pA[f] + 198) * 4];
                #pragma unroll
                for (int j = 0; j < 4; ++j) { a[j] = alo[j]; a[4 + j] = ahi[j]; }
            }
            acc[f][0] = __builtin_amdgcn_mfma_f32_16x16x32_f16(a, b0, acc[f][0], 0, 0, 0);
            acc[f][1] = __builtin_amdgcn_mfma_f32_16x16x32_f16(a, b1, acc[f][1], 0, 0, 0);
        }
    }

    float bv0 = bias[lm];
    float bv1 = bias[16 + lm];
    float s0 = 0.f, s20 = 0.f, s1 = 0.f, s21 = 0.f;
    #pragma unroll
    for (int f = 0; f < 4; ++f) {
        #pragma unroll
        for (int r = 0; r < 4; ++r) {
            float v0 = acc[f][0][r] + bv0;
            float v1 = acc[f][1][r] + bv1;
            int p_loc = w * 64 + f * 16 + lg * 4 + r;
            s_y[p_loc * 32 + lm] = (_Float16)v0;
            s_y[p_loc * 32 + 16 + lm] = (_Float16)v1;
            s0 += v0; s20 += v0 * v0;
            s1 += v1; s21 += v1 * v1;
        }
    }
    s0 += __shfl_xor(s0, 16);  s0 += __shfl_xor(s0, 32);
    s1 += __shfl_xor(s1, 16);  s1 += __shfl_xor(s1, 32);
    s20 += __shfl_xor(s20, 16); s20 += __shfl_xor(s20, 32);
    s21 += __shfl_xor(s21, 16); s21 += __shfl_xor(s21, 32);
    if (l < 16) {
        atomicAdd(&s_red[lm], s0);
        atomicAdd(&s_red[16 + lm], s1);
        atomicAdd(&s_red[32 + lm], s20);
        atomicAdd(&s_red[48 + lm], s21);
    }
    __syncthreads();

    // coalesced Y store: 4 rows x 64 cols x 32 ch contiguous
    {
        _Float16* Yb = Yg + ((size_t)(n * 64 + row0) * 64) * 32;
        #pragma unroll
        for (int i = 0; i < 4; ++i) {
            int idx = t + 256 * i;
            *(half8*)&Yb[(size_t)idx * 8] = *(const half8*)&s_y[idx * 8];
        }
    }
    if (t < 64)
        partials[((size_t)n * 16 + blockIdx.x) * 64 + t] = s_red[t];
}

// ---------------------------------------------------------------------------
// conv2 FUSED v7: stages bn1(Yg)+relu tile from global (fused scale/shift at
// load). LDS 47.8 KB -> 3 blocks/CU. 512 thr, ROWS=8; grid (8,1,256).
// ---------------------------------------------------------------------------
__global__ __launch_bounds__(512, 6) void conv2_fused_kernel(
    const _Float16* __restrict__ Yg, const _Float16* __restrict__ ssh1,
    const _Float16* __restrict__ wt2, const float* __restrict__ c2bias,
    _Float16* __restrict__ out0, _Float16* __restrict__ out1,
    float* __restrict__ partials)
{
    constexpr int COUT = 32, MF = 4, NB = 2;
    constexpr int ROWS = 8;
    constexpr int TC = 66, NPIX = 10 * 66;         // 660
    constexpr int PS = 36;                          // pixel stride (halves)
    __shared__ __align__(16) _Float16 s_in[NPIX * PS];   // 47,520 B
    __shared__ float s_red[64];

    const int t = threadIdx.x;
    const int row0 = blockIdx.x * ROWS;
    const int n = blockIdx.z;
    const int w = t >> 6, l = t & 63;
    const int lm = l & 15, lg = l >> 4;

    if (t < 64) s_red[t] = 0.f;

    // ---- stage relu(bn1(Y)) tile: rows row0-1..row0+8, cols -1..64 ----
    {
        const int c8 = t & 3;                       // constant: 512 % 4 == 0
        half8 sc = *(const half8*)&ssh1[c8 * 8];
        half8 sh = *(const half8*)&ssh1[32 + c8 * 8];
        for (int idx = t; idx < NPIX * 4; idx += 512) {
            int p = idx >> 2;
            int py = p / 66, px = p - py * 66;
            int gy = row0 - 1 + py, gx = px - 1;
            half8 v;
            #pragma unroll
            for (int j = 0; j < 8; ++j) v[j] = (_Float16)0.f;
            if (gy >= 0 && gy < 64 && gx >= 0 && gx < 64) {
                half8 y = *(const half8*)&Yg[(((size_t)n * 64 + gy) * 64 + gx) * 32 + c8 * 8];
                #pragma unroll
                for (int j = 0; j < 8; ++j) {
                    _Float16 f = y[j] * sc[j] + sh[j];
                    v[j] = f > (_Float16)0.f ? f : (_Float16)0.f;
                }
            }
            half4* vp = (half4*)&v;
            *(half4*)&s_in[p * PS + c8 * 8] = vp[0];
            *(half4*)&s_in[p * PS + c8 * 8 + 4] = vp[1];
        }
    }
    __syncthreads();

    // ---- conv2 main compute: wave = output row (row0+w), columns f*16+lm ----
    int pA[MF];
    #pragma unroll
    for (int f = 0; f < MF; ++f)
        pA[f] = w * TC + f * 16 + lm;
    f32x4 zero4 = {0.f, 0.f, 0.f, 0.f};
    f32x4 acc[MF][NB];
    #pragma unroll
    for (int f = 0; f < MF; ++f)
        #pragma unroll
        for (int nb = 0; nb < NB; ++nb) acc[f][nb] = zero4;

    #pragma unroll
    for (int tap = 0; tap < 9; ++tap) {
        const int dy = tap / 3, dx = tap % 3;
        const int poff = dy * TC + dx;
        half8 b[NB];
        #pragma unroll
        for (int nb = 0; nb < NB; ++nb) {
            int col = nb * 16 + lm;
            b[nb] = *(const half8*)&wt2[((tap * 4 + lg) * 32 + col) * 8];
        }
        #pragma unroll
        for (int f = 0; f < MF; ++f) {
            int p = pA[f] + poff;
            half4 alo = *(const half4*)&s_in[p * PS + lg * 8];
            half4 ahi = *(const half4*)&s_in[p * PS + lg * 8 + 4];
            half8 a;
            #pragma unroll
            for (int j = 0; j < 4; ++j) { a[j] = alo[j]; a[4 + j] = ahi[j]; }
            #pragma unroll
            for (int nb = 0; nb < NB; ++nb)
                acc[f][nb] = __builtin_amdgcn_mfma_f32_16x16x32_f16(a, b[nb], acc[f][nb], 0, 0, 0);
        }
    }

    // ---- bias fold + stats (registers only) ----
    float bv[NB], s[NB], s2[NB];
    #pragma unroll
    for (int nb = 0; nb < NB; ++nb) {
        bv[nb] = c2bias[nb * 16 + lm];
        s[nb] = 0.f; s2[nb] = 0.f;
    }
    #pragma unroll
    for (int f = 0; f < MF; ++f) {
        #pragma unroll
        for (int nb = 0; nb < NB; ++nb) {
            #pragma unroll
            for (int r = 0; r < 4; ++r) {
                float v = acc[f][nb][r] + bv[nb];
                acc[f][nb][r] = v;
                s[nb] += v; s2[nb] += v * v;
            }
        }
    }
    #pragma unroll
    for (int nb = 0; nb < NB; ++nb) {
        s[nb] += __shfl_xor(s[nb], 16);  s[nb] += __shfl_xor(s[nb], 32);
        s2[nb] += __shfl_xor(s2[nb], 16); s2[nb] += __shfl_xor(s2[nb], 32);
    }
    if (l < 16) {
        #pragma unroll
        for (int nb = 0; nb < NB; ++nb) {
            atomicAdd(&s_red[nb * 16 + lm], s[nb]);
            atomicAdd(&s_red[32 + nb * 16 + lm], s2[nb]);
        }
    }

    // ---- pool: h-pool in lane -> pk rows -> vertical gather -> stores ----
    {
        __syncthreads();                    // all MFMA reads of s_in done
        _Float16* pk = s_in;                // [8 rows][32 xp][32 ch] min, +8192 max
        #pragma unroll
        for (int nb = 0; nb < NB; ++nb) {
            #pragma unroll
            for (int f = 0; f < MF; ++f) {
                float v0 = acc[f][nb][0], v1 = acc[f][nb][1];
                float v2 = acc[f][nb][2], v3 = acc[f][nb][3];
                int xp0 = f * 8 + lg * 2;
                int o0 = (w * 32 + xp0) * COUT + nb * 16 + lm;
                int o1 = (w * 32 + xp0 + 1) * COUT + nb * 16 + lm;
                pk[o0] = (_Float16)fminf(v0, v1);
                pk[8192 + o0] = (_Float16)fmaxf(v0, v1);
                pk[o1] = (_Float16)fminf(v2, v3);
                pk[8192 + o1] = (_Float16)fmaxf(v2, v3);
            }
        }
        __syncthreads();
        // vertical gather: 4 pooled rows x 32 xp x 4 c8 = 512 threads
        int hp_row = t >> 7, rem = t & 127;
        int xp = rem >> 2, c8 = rem & 3;
        half8 mnA = *(const half8*)&pk[((2 * hp_row) * 32 + xp) * COUT + c8 * 8];
        half8 mnB = *(const half8*)&pk[((2 * hp_row + 1) * 32 + xp) * COUT + c8 * 8];
        half8 mxA = *(const half8*)&pk[8192 + ((2 * hp_row) * 32 + xp) * COUT + c8 * 8];
        half8 mxB = *(const half8*)&pk[8192 + ((2 * hp_row + 1) * 32 + xp) * COUT + c8 * 8];
        half8 mn, mx;
        #pragma unroll
        for (int j = 0; j < 8; ++j) {
            mn[j] = mnA[j] < mnB[j] ? mnA[j] : mnB[j];
            mx[j] = mxA[j] > mxB[j] ? mxA[j] : mxB[j];
        }
        size_t ob = (((size_t)n * 32 + (row0 >> 1) + hp_row) * 32 + xp) * COUT + c8 * 8;
        *(half8*)&out0[ob] = mn;
        *(half8*)&out1[ob] = mx;
    }

    __syncthreads();
    if (t < 64) {
        size_t bid = (size_t)n * gridDim.x + blockIdx.x;
        partials[bid * 64 + t] = s_red[t];
    }
}

// ---------------------------------------------------------------------------
// Implicit-GEMM 3x3 conv via MFMA (single-pass staging). Used for conv3/conv4.
// ---------------------------------------------------------------------------
template<int BLOCK, int W, int CIN, int COUT, int MF, int NB,
         bool MMIN, bool POOL>
__global__ __launch_bounds__(BLOCK, (BLOCK == 512 ? 4 : 3)) void conv_mfma_kernel(
    const _Float16* __restrict__ in0, const _Float16* __restrict__ in1,
    const _Float16* __restrict__ coef, const _Float16* __restrict__ wt,
    const float* __restrict__ bias,
    _Float16* __restrict__ out0, _Float16* __restrict__ out1,
    float* __restrict__ partials)
{
    constexpr int H = W;
    constexpr int NWAVE = BLOCK / 64;
    constexpr int SPW = MF * 16;
    constexpr int ROWS = NWAVE * SPW / W;
    constexpr int TR = ROWS + 2;
    constexpr int TC = W + 2;
    constexpr int NPIX = TR * TC;
    constexpr int NCH = CIN / 32;
    constexpr int C8N = CIN / 8;
    constexpr int KC = 288;
    constexpr int COUTB = NB * 16;
    __shared__ __align__(16) _Float16 s_in[NPIX * CIN];
    __shared__ float s_red[2 * COUTB];

    const int t = threadIdx.x;
    const int row0 = blockIdx.x * ROWS;
    const int n = blockIdx.z;

    const int w = t >> 6, l = t & 63;
    const int lm = l & 15, lg = l >> 4;
    int pA[MF];
    #pragma unroll
    for (int f = 0; f < MF; ++f) {
        int m = w * SPW + f * 16 + lm;
        pA[f] = (m / W) * TC + (m % W);
    }
    f32x4 zero4 = {0.f, 0.f, 0.f, 0.f};
    f32x4 acc[MF][NB];
    #pragma unroll
    for (int f = 0; f < MF; ++f)
        #pragma unroll
        for (int nb = 0; nb < NB; ++nb) acc[f][nb] = zero4;
    if (t < 2 * COUTB) s_red[t] = 0.f;

    for (int idx = t; idx < NPIX * C8N; idx += BLOCK) {
        int c8 = idx % C8N;
        int p = idx / C8N;
        int col = p % TC, r = p / TC;
        int gy = row0 + r - 1, gx = col - 1;
        half8 v;
        #pragma unroll
        for (int j = 0; j < 8; ++j) v[j] = (_Float16)0.f;
        if (gy >= 0 && gy < H && gx >= 0 && gx < W) {
            size_t gidx = (((size_t)n * H + gy) * W + gx) * CIN + c8 * 8;
            if (MMIN) {
                half8 mn = *(const half8*)&in0[gidx];
                half8 mx = *(const half8*)&in1[gidx];
                half8 sa = *(const half8*)&coef[c8 * 8];
                half8 sb = *(const half8*)&coef[CIN + c8 * 8];
                half8 sh = *(const half8*)&coef[2 * CIN + c8 * 8];
                #pragma unroll
                for (int j = 0; j < 8; ++j) {
                    _Float16 f = mx[j] * sa[j] + mn[j] * sb[j] + sh[j];
                    v[j] = f > (_Float16)0.f ? f : (_Float16)0.f;
                }
            } else {
                v = *(const half8*)&in0[gidx];
                if (coef) {
                    half8 sc = *(const half8*)&coef[c8 * 8];
                    half8 sh = *(const half8*)&coef[CIN + c8 * 8];
                    #pragma unroll
                    for (int j = 0; j < 8; ++j) {
                        _Float16 f = v[j] * sc[j] + sh[j];
                        v[j] = f > (_Float16)0.f ? f : (_Float16)0.f;
                    }
                }
            }
        }
        *(half8*)&s_in[(c8 * NPIX + p) * 8] = v;
    }
    __syncthreads();

    #pragma unroll
    for (int tap = 0; tap < 9; ++tap) {
        const int dy = tap / 3, dx = tap % 3;
        const int poff = dy * TC + dx;
        #pragma unroll
        for (int cc = 0; cc < NCH; ++cc) {
            half8 b[NB];
            #pragma unroll
            for (int nb = 0; nb < NB; ++nb) {
                int cog = nb * 16 + lm;
                int gg = cog >> 5, col = cog & 31;
                const _Float16* wp = wt + (size_t)(gg * NCH + cc) * KC * 32;
                b[nb] = *(const half8*)&wp[((tap * 4 + lg) * 32 + col) * 8];
            }
            #pragma unroll
            for (int f = 0; f < MF; ++f) {
                half8 a = *(const half8*)&s_in[((cc * 4 + lg) * NPIX + pA[f] + poff) * 8];
                #pragma unroll
                for (int nb = 0; nb < NB; ++nb)
                    acc[f][nb] = __builtin_amdgcn_mfma_f32_16x16x32_f16(a, b[nb], acc[f][nb], 0, 0, 0);
            }
        }
    }

    float bv[NB], s[NB], s2[NB];
    #pragma unroll
    for (int nb = 0; nb < NB; ++nb) {
        bv[nb] = bias[nb * 16 + lm];
        s[nb] = 0.f; s2[nb] = 0.f;
    }
    #pragma unroll
    for (int f = 0; f < MF; ++f) {
        #pragma unroll
        for (int r = 0; r < 4; ++r) {
            int m = w * SPW + f * 16 + lg * 4 + r;
            int yy = row0 + m / W, xo = m % W;
            size_t base = (((size_t)n * H + yy) * W + xo) * COUT;
            #pragma unroll
            for (int nb = 0; nb < NB; ++nb) {
                float v = acc[f][nb][r] + bv[nb];
                if (!POOL) out0[base + nb * 16 + lm] = (_Float16)v;
                s[nb] += v; s2[nb] += v * v;
            }
        }
    }
    #pragma unroll
    for (int nb = 0; nb < NB; ++nb) {
        s[nb] += __shfl_xor(s[nb], 16);  s[nb] += __shfl_xor(s[nb], 32);
        s2[nb] += __shfl_xor(s2[nb], 16); s2[nb] += __shfl_xor(s2[nb], 32);
    }
    if (l < 16) {
        #pragma unroll
        for (int nb = 0; nb < NB; ++nb) {
            atomicAdd(&s_red[nb * 16 + lm], s[nb]);
            atomicAdd(&s_red[COUTB + nb * 16 + lm], s2[nb]);
        }
    }

    if (POOL) {
        constexpr int FH = MF / 2;
        constexpr int PPIX = (ROWS / 2) * (W / 2);
        static_assert(2 * PPIX * COUT <= NPIX * CIN, "pool pack fits in s_in");
        __syncthreads();
        _Float16* pk = s_in;
        #pragma unroll
        for (int nb = 0; nb < NB; ++nb) {
            #pragma unroll
            for (int f = 0; f < FH; ++f) {
                #pragma unroll
                for (int rp = 0; rp < 2; ++rp) {
                    float a0 = acc[f][nb][2 * rp] + bv[nb];
                    float a1 = acc[f][nb][2 * rp + 1] + bv[nb];
                    float a2 = acc[f + FH][nb][2 * rp] + bv[nb];
                    float a3 = acc[f + FH][nb][2 * rp + 1] + bv[nb];
                    float mn = fminf(fminf(a0, a1), fminf(a2, a3));
                    float mx = fmaxf(fmaxf(a0, a1), fmaxf(a2, a3));
                    int xp = f * 8 + lg * 2 + rp;
                    int o = (w * (W / 2) + xp) * COUT + nb * 16 + lm;
                    pk[o] = (_Float16)mn;
                    pk[PPIX * COUT + o] = (_Float16)mx;
                }
            }
        }
        __syncthreads();
        size_t gb = (((size_t)n * (H / 2) + (row0 >> 1)) * (W / 2)) * COUT;
        for (int idx = t; idx < PPIX * COUT / 8; idx += BLOCK) {
            *(half8*)&out0[gb + (size_t)idx * 8] = *(const half8*)&pk[idx * 8];
            *(half8*)&out1[gb + (size_t)idx * 8] = *(const half8*)&pk[(PPIX * COUT + idx * 8)];
        }
    }

    __syncthreads();
    if (t < 2 * COUTB) {
        size_t bid = (size_t)n * gridDim.x + blockIdx.x;
        partials[bid * 2 * COUTB + t] = s_red[t];
    }
}

// ---------------------------------------------------------------------------
// Reduce per-block partials -> BN coefficients. Record = [sum C | sumsq C].
// ---------------------------------------------------------------------------
__global__ __launch_bounds__(256) void bn_finalize_kernel(
    const float* __restrict__ partials, int nx, float inv_count,
    const float* __restrict__ gamma, const float* __restrict__ beta,
    float* __restrict__ ss, _Float16* __restrict__ ssh,
    _Float16* __restrict__ sab, int COUT)
{
    const int c = blockIdx.x;
    const int t = threadIdx.x;
    float sum = 0.f, sq = 0.f;
    int total = 256 * nx;
    for (int e = t; e < total; e += 256) {
        size_t off = (size_t)e * 2 * COUT;
        sum += partials[off + c];
        sq  += partials[off + COUT + c];
    }
    #pragma unroll
    for (int off = 32; off > 0; off >>= 1) {
        sum += __shfl_xor(sum, off);
        sq  += __shfl_xor(sq, off);
    }
    __shared__ float rs[4], rq[4];
    if ((t & 63) == 0) { rs[t >> 6] = sum; rq[t >> 6] = sq; }
    __syncthreads();
    if (t == 0) {
        sum = rs[0] + rs[1] + rs[2] + rs[3];
        sq  = rq[0] + rq[1] + rq[2] + rq[3];
        float mean = sum * inv_count;
        float var = sq * inv_count - mean * mean;
        float scale = gamma[c] * rsqrtf(var + 1e-5f);
        float shift = beta[c] - mean * scale;
        ss[c] = scale;
        ss[COUT + c] = shift;
        if (ssh) {
            ssh[c] = (_Float16)scale;
            ssh[COUT + c] = (_Float16)shift;
        }
        if (sab) {
            sab[c] = (_Float16)(scale > 0.f ? scale : 0.f);
            sab[COUT + c] = (_Float16)(scale > 0.f ? 0.f : scale);
            sab[2 * COUT + c] = (_Float16)shift;
        }
    }
}

// ---------------------------------------------------------------------------
// fc1 MFMA GEMM (K-split): A = relu(bn4(pooled minmax pair)) on the fly.
// ---------------------------------------------------------------------------
__global__ __launch_bounds__(256) void fc1_mfma_kernel(
    const _Float16* __restrict__ Amin, const _Float16* __restrict__ Amax,
    const _Float16* __restrict__ sab, const _Float16* __restrict__ Bw,
    float* __restrict__ hp)
{
    __shared__ __align__(16) _Float16 As[64][72];
    __shared__ __align__(16) _Float16 Bs[128][72];
    const int t = threadIdx.x;
    const int mt = blockIdx.x;
    const int kc = blockIdx.y;
    const int w = t >> 6, l = t & 63;
    const int lm = l & 15, lg = l >> 4;

    f32x4 zero4 = {0.f, 0.f, 0.f, 0.f};
    f32x4 acc[8];
    #pragma unroll
    for (int nb = 0; nb < 8; ++nb) acc[nb] = zero4;

    const size_t a_base = (size_t)(mt * 64) * 16384 + (size_t)kc * 512;
    const size_t b_base = (size_t)kc * 512;

    for (int p = 0; p < 8; ++p) {
        __syncthreads();
        #pragma unroll
        for (int i = 0; i < 2; ++i) {
            int idx = t + 256 * i;
            int r = idx >> 3, c8 = idx & 7;
            size_t off = a_base + (size_t)r * 16384 + p * 64 + c8 * 8;
            half8 mn = *(const half8*)&Amin[off];
            half8 mx = *(const half8*)&Amax[off];
            half8 sa = *(const half8*)&sab[c8 * 8];
            half8 sb = *(const half8*)&sab[64 + c8 * 8];
            half8 sh = *(const half8*)&sab[128 + c8 * 8];
            half8 v;
            #pragma unroll
            for (int j = 0; j < 8; ++j) {
                _Float16 f = mx[j] * sa[j] + mn[j] * sb[j] + sh[j];
                v[j] = f > (_Float16)0.f ? f : (_Float16)0.f;
            }
            *(half8*)&As[r][c8 * 8] = v;
        }
        #pragma unroll
        for (int i = 0; i < 4; ++i) {
            int idx = t + 256 * i;
            int r = idx >> 3, c8 = idx & 7;
            *(half8*)&Bs[r][c8 * 8] =
                *(const half8*)&Bw[b_base + (size_t)r * 16384 + p * 64 + c8 * 8];
        }
        __syncthreads();
        #pragma unroll
        for (int ks = 0; ks < 64; ks += 32) {
            half8 a = *(const half8*)&As[w * 16 + lm][ks + lg * 8];
            #pragma unroll
            for (int nb = 0; nb < 8; ++nb) {
                half8 b = *(const half8*)&Bs[nb * 16 + lm][ks + lg * 8];
                acc[nb] = __builtin_amdgcn_mfma_f32_16x16x32_f16(a, b, acc[nb], 0, 0, 0);
            }
        }
    }
    #pragma unroll
    for (int nb = 0; nb < 8; ++nb) {
        #pragma unroll
        for (int r = 0; r < 4; ++r) {
            int row = mt * 64 + w * 16 + lg * 4 + r;
            hp[((size_t)kc * 256 + row) * 128 + nb * 16 + lm] = acc[nb][r];
        }
    }
}

// ---------------------------------------------------------------------------
// fc1 reduce + relu + fc2 + quantum circuit + head, one block per batch n.
// 256 threads = 4 waves; quantum state spread over 4 waves (4 amps/lane):
// amp = (r<<8)|(wv<<6)|lane. Gates: bits 8-9 in-register, bits 6-7 LDS
// cross-wave exchange, bits 0-5 shfl_xor.
// ---------------------------------------------------------------------------
__global__ __launch_bounds__(256) void fcq_kernel(
    const float* __restrict__ hp, const float* __restrict__ f1b,
    const float* __restrict__ f2w, const float* __restrict__ f2b,
    const float* __restrict__ rotm, const unsigned short* __restrict__ perm,
    const float* __restrict__ head_w, const float* __restrict__ head_b,
    float* __restrict__ outp)
{
    __shared__ float lre[1024];
    __shared__ float lim[1024];
    __shared__ float hl[128];
    __shared__ float xql[10];
    const int n = blockIdx.x;
    const int t = threadIdx.x;
    const int l = t & 63;
    const int wv = t >> 6;

    // ---- fc1 reduce + bias + relu (exact original order, t<128) ----
    if (t < 128) {
        float s = f1b[t];
        #pragma unroll
        for (int kc = 0; kc < 32; ++kc) s += hp[((size_t)kc * 256 + n) * 128 + t];
        hl[t] = fmaxf(0.f, s);
    }
    __syncthreads();
    // ---- fc2 ----
    if (t < 10) {
        float o = f2b[t];
        #pragma unroll 4
        for (int k = 0; k < 128; ++k) o += f2w[t * 128 + k] * hl[k];
        xql[t] = o;
    }
    __syncthreads();

    // ---- quantum: 4 amps/lane, amp = (r<<8)|(wv<<6)|l ----
    const int ampb = (wv << 6) | l;          // low 8 bits of amp (r adds <<8)
    float ar[4], ai[4];
    #pragma unroll
    for (int r = 0; r < 4; ++r) { ar[r] = 0.f; ai[r] = 0.f; }
    if (t == 0) ar[0] = 1.f;

    // RY embedding layer (real amplitudes)
    #pragma unroll
    for (int w = 0; w < 10; ++w) {
        float th = 0.5f * PI_F * xql[w];
        float c = cosf(th), s = sinf(th);
        const int k = 9 - w;
        if (k >= 8) {
            const int b = k - 8;
            #pragma unroll
            for (int r = 0; r < 4; ++r) {
                if (!(r & (1 << b))) {
                    int r1 = r | (1 << b);
                    float a0 = ar[r], a1 = ar[r1];
                    ar[r]  = c * a0 - s * a1;
                    ar[r1] = s * a0 + c * a1;
                }
            }
        } else if (k >= 6) {
            #pragma unroll
            for (int r = 0; r < 4; ++r) lre[(r << 8) | ampb] = ar[r];
            __syncthreads();
            float ss = ((wv >> (k - 6)) & 1) ? s : -s;
            #pragma unroll
            for (int r = 0; r < 4; ++r) {
                float p = lre[((r << 8) | ampb) ^ (1 << k)];
                ar[r] = c * ar[r] + ss * p;
            }
            __syncthreads();
        } else {
            float ss = ((l >> k) & 1) ? s : -s;
            #pragma unroll
            for (int r = 0; r < 4; ++r) {
                float p = __shfl_xor(ar[r], 1 << k);
                ar[r] = c * ar[r] + ss * p;
            }
        }
    }

    #pragma unroll 1
    for (int layer = 0; layer < 6; ++layer) {
        #pragma unroll
        for (int w = 0; w < 10; ++w) {
            const float* m = rotm + (layer * 10 + w) * 8;
            float m00r = m[0], m00i = m[1], m01r = m[2], m01i = m[3];
            float m10r = m[4], m10i = m[5], m11r = m[6], m11i = m[7];
            const int k = 9 - w;
            if (k >= 8) {
                const int b = k - 8;
                #pragma unroll
                for (int r = 0; r < 4; ++r) {
                    if (!(r & (1 << b))) {
                        int r1 = r | (1 << b);
                        float a0r = ar[r], a0i = ai[r];
                        float a1r = ar[r1], a1i = ai[r1];
                        ar[r]  = m00r * a0r - m00i * a0i + m01r * a1r - m01i * a1i;
                        ai[r]  = m00r * a0i + m00i * a0r + m01r * a1i + m01i * a1r;
                        ar[r1] = m10r * a0r - m10i * a0i + m11r * a1r - m11i * a1i;
                        ai[r1] = m10r * a0i + m10i * a0r + m11r * a1i + m11i * a1r;
                    }
                }
            } else if (k >= 6) {
                #pragma unroll
                for (int r = 0; r < 4; ++r) {
                    lre[(r << 8) | ampb] = ar[r];
                    lim[(r << 8) | ampb] = ai[r];
                }
                __syncthreads();
                int bit = (wv >> (k - 6)) & 1;
                float mAr = bit ? m11r : m00r, mAi = bit ? m11i : m00i;
                float mBr = bit ? m10r : m01r, mBi = bit ? m10i : m01i;
                #pragma unroll
                for (int r = 0; r < 4; ++r) {
                    int pa = ((r << 8) | ampb) ^ (1 << k);
                    float pr = lre[pa], pi = lim[pa];
                    float mr = ar[r], mi = ai[r];
                    ar[r] = mAr * mr - mAi * mi + mBr * pr - mBi * pi;
                    ai[r] = mAr * mi + mAi * mr + mBr * pi + mBi * pr;
                }
                __syncthreads();
            } else {
                int bit = (l >> k) & 1;
                float mAr = bit ? m11r : m00r, mAi = bit ? m11i : m00i;
                float mBr = bit ? m10r : m01r, mBi = bit ? m10i : m01i;
                #pragma unroll
                for (int r = 0; r < 4; ++r) {
                    float pr = __shfl_xor(ar[r], 1 << k);
                    float pi = __shfl_xor(ai[r], 1 << k);
                    float mr = ar[r], mi = ai[r];
                    ar[r] = mAr * mr - mAi * mi + mBr * pr - mBi * pi;
                    ai[r] = mAr * mi + mAi * mr + mBr * pi + mBi * pr;
                }
            }
        }
        // layer permutation
        #pragma unroll
        for (int r = 0; r < 4; ++r) {
            lre[(r << 8) | ampb] = ar[r];
            lim[(r << 8) | ampb] = ai[r];
        }
        __syncthreads();
        const unsigned short* pt = perm + layer * 1024;
        #pragma unroll
        for (int r = 0; r < 4; ++r) {
            int ji = pt[(r << 8) | ampb];
            ar[r] = lre[ji];
            ai[r] = lim[ji];
        }
        __syncthreads();
    }

    // ---- Z expectations + head ----
    float S = 0.f, T9 = 0.f, T8 = 0.f;
    #pragma unroll
    for (int r = 0; r < 4; ++r) {
        float pr = ar[r] * ar[r] + ai[r] * ai[r];
        S += pr;
        T9 += (r & 2) ? -pr : pr;       // amp bit9 -> wire 0
        T8 += (r & 1) ? -pr : pr;       // amp bit8 -> wire 1
    }
    float pk[10];
    pk[0] = T9;
    pk[1] = T8;
    pk[2] = ((wv >> 1) & 1) ? -S : S;   // amp bit7 -> wire 2
    pk[3] = (wv & 1) ? -S : S;          // amp bit6 -> wire 3
    #pragma unroll
    for (int w = 4; w < 10; ++w)
        pk[w] = ((l >> (9 - w)) & 1) ? -S : S;
    #pragma unroll
    for (int w = 0; w < 10; ++w) {
        #pragma unroll
        for (int off = 1; off < 64; off <<= 1)
            pk[w] += __shfl_xor(pk[w], off);
    }
    if (l == 0) {
        #pragma unroll
        for (int w = 0; w < 10; ++w) lre[wv * 16 + w] = pk[w];
    }
    __syncthreads();
    if (t < 10) {
        float tot = lre[t] + lre[16 + t] + lre[32 + t] + lre[48 + t];
        lre[64 + t] = tot;
    }
    __syncthreads();
    if (t < 10) {
        float o = head_b[t];
        #pragma unroll
        for (int kk = 0; kk < 10; ++kk) o += lre[64 + kk] * head_w[t * 10 + kk];
        outp[n * 10 + t] = o;
    }
}

// ---------------------------------------------------------------------------
extern "C" void kernel_launch(void* const* d_in, const int* in_sizes, int n_in,
                              void* d_out, int out_size, void* d_ws, size_t ws_size,
                              hipStream_t stream)
{
    const float* x   = (const float*)d_in[0];
    const float* c1w = (const float*)d_in[1];  const float* c1b = (const float*)d_in[2];
    const float* g1  = (const float*)d_in[3];  const float* b1  = (const float*)d_in[4];
    const float* c2w = (const float*)d_in[5];  const float* c2b = (const float*)d_in[6];
    const float* g2  = (const float*)d_in[7];  const float* b2  = (const float*)d_in[8];
    const float* c3w = (const float*)d_in[9];  const float* c3b = (const float*)d_in[10];
    const float* g3  = (const float*)d_in[11]; const float* b3  = (const float*)d_in[12];
    const float* c4w = (const float*)d_in[13]; const float* c4b = (const float*)d_in[14];
    const float* g4  = (const float*)d_in[15]; const float* b4  = (const float*)d_in[16];
    const float* f1w = (const float*)d_in[17]; const float* f1b = (const float*)d_in[18];
    const float* f2w = (const float*)d_in[19]; const float* f2b = (const float*)d_in[20];
    const float* qw  = (const float*)d_in[21];
    const float* hw  = (const float*)d_in[22]; const float* hb  = (const float*)d_in[23];

    float* ws = (float*)d_ws;
    _Float16* H0 = (_Float16*)ws;              // 33,554,432 halves (67 MB)
    _Float16* H1 = H0 + 33554432;              // 33,554,432 halves (67 MB)
    float* part = ws + 33554432;               // 524,288
    float* ss1  = part + 524288;               // 64
    float* ss2  = ss1 + 64;                    // 64
    float* ss3  = ss2 + 64;                    // 128
    float* ss4  = ss3 + 128;                   // 128
    float* hp   = ss4 + 128;                   // 1,048,576
    float* rotm = hp + 1048576;                // 480
    unsigned short* perm16 = (unsigned short*)(rotm + 480);   // 6,144 u16
    _Float16* ssh1 = (_Float16*)(perm16 + 6144);   // 64 halves
    _Float16* ssh3 = ssh1 + 64;                // 128
    _Float16* sab2 = ssh3 + 128;               // 96
    _Float16* sab4 = sab2 + 96;                // 192
    _Float16* wt2  = sab4 + 192;               // 9,216
    _Float16* wt3  = wt2 + 9216;               // 18,432
    _Float16* wt4  = wt3 + 18432;              // 36,864
    _Float16* w1m  = wt4 + 36864;              // 2,048
    _Float16* w1t  = w1m + 2048;               // 2,097,152
    _Float16* X4P  = w1t + 2097152;            // 4,874,240 (256*70*68*4, 9.75 MB)

    // overlays (sequential lifetimes):
    //  Yg (conv1+bias fp16, 256x64x64x32 = 33.5M halves) = H0; dead once conv2
    //  completes; conv3 then writes its output into H0.
    _Float16* Yg    = H0;
    _Float16* minT2 = H1;                      // (256,32,32,32)
    _Float16* maxT2 = H1 + 8388608;
    _Float16* minT4 = H1;                      // (256,16,16,64)
    _Float16* maxT4 = H1 + 4194304;

    // unified one-time prep
    prep_kernel<<<3153, 256, 0, stream>>>(x, X4P, c1w, c2w, c3w, c4w,
                                          w1m, wt2, wt3, wt4, f1w, w1t,
                                          qw, rotm, perm16);

    // conv1: Y = fp16(conv1+bias) -> Yg (H0) + BN1 stats
    conv1_stats_kernel<<<dim3(16, 1, 256), 256, 0, stream>>>(
        X4P, w1m, c1b, Yg, part);
    bn_finalize_kernel<<<32, 256, 0, stream>>>(part, 16, 1.f / 1048576.f,
                                               g1, b1, ss1, ssh1, nullptr, 32);

    // conv2 FUSED v7 (stages relu(bn1(Yg)) from global): -> minT2/maxT2 + stats
    conv2_fused_kernel<<<dim3(8, 1, 256), 512, 0, stream>>>(
        Yg, ssh1, wt2, c2b, minT2, maxT2, part);
    bn_finalize_kernel<<<32, 256, 0, stream>>>(part, 8, 1.f / 1048576.f,
                                               g2, b2, ss2, nullptr, sab2, 32);

    // conv3 (512thr, 64 cout/wave, minmax input): relu(bn2(pool1)) -> H0
    conv_mfma_kernel<512, 32, 32, 64, 4, 4, true, false>
        <<<dim3(2, 1, 256), 512, 0, stream>>>(
        minT2, maxT2, sab2, wt3, c3b, H0, nullptr, part);
    bn_finalize_kernel<<<64, 256, 0, stream>>>(part, 2, 1.f / 262144.f,
                                               g3, b3, ss3, ssh3, nullptr, 64);

    // conv4 (512thr, single-pass CIN=64 staging, packed pooled stores)
    conv_mfma_kernel<512, 32, 64, 64, 4, 4, false, true>
        <<<dim3(2, 1, 256), 512, 0, stream>>>(
        H0, nullptr, ssh3, wt4, c4b, minT4, maxT4, part);
    bn_finalize_kernel<<<64, 256, 0, stream>>>(part, 2, 1.f / 262144.f,
                                               g4, b4, ss4, nullptr, sab4, 64);

    // fc1: MFMA GEMM with on-the-fly relu(bn4(pool2))
    fc1_mfma_kernel<<<dim3(4, 32), 256, 0, stream>>>(minT4, maxT4, sab4, w1t, hp);

    // fc1-reduce + fc2 + quantum circuit (4-wave) + head -> out (256,10)
    fcq_kernel<<<256, 256, 0, stream>>>(hp, f1b, f2w, f2b,
                                        rotm, perm16, hw, hb, (float*)d_out);
}

// Round 24
// 184.163 us; speedup vs baseline: 1.0581x; 1.0011x over previous
//
#include <hip/hip_runtime.h>
#include <math.h>

#define PI_F 3.14159265358979323846f

typedef __attribute__((ext_vector_type(8))) _Float16 half8;
typedef __attribute__((ext_vector_type(4))) _Float16 half4;
typedef __attribute__((ext_vector_type(4))) float f32x4;

// ---------------------------------------------------------------------------
// Unified prep kernel, grid 3153x256:
//  [0,2380)    x (256,3,64,64) fp32 -> X4P (256,70,68,4) fp16, zero border
//  [2380,2640) conv weight transforms (channel-blocked fp16)
//  [2640,3152) fc1 weight transform (NCHW-k -> NHWC-k fp16)
//  [3152]      quantum prep: 60 Rot matrices + 6x1024 u16 perm table
// ---------------------------------------------------------------------------
__global__ __launch_bounds__(256) void prep_kernel(
    const float* __restrict__ x, _Float16* __restrict__ X4P,
    const float* __restrict__ w1, const float* __restrict__ w2,
    const float* __restrict__ w3, const float* __restrict__ w4,
    _Float16* __restrict__ t1, _Float16* __restrict__ t2,
    _Float16* __restrict__ t3, _Float16* __restrict__ t4,
    const float* __restrict__ f1w, _Float16* __restrict__ w1t,
    const float* __restrict__ qw, float* __restrict__ rotm,
    unsigned short* __restrict__ perm)
{
    const int b = blockIdx.x;
    const int t = threadIdx.x;
    if (b < 2380) {
        int pp = (b * 256 + t) * 2;          // 2 pixels per thread
        half8 o;
        #pragma unroll
        for (int j = 0; j < 2; ++j) {
            int p = pp + j;
            int n = p / 4760;
            int rem = p - n * 4760;
            int yp = rem / 68, xp = rem - (rem / 68) * 68;
            int gy = yp - 2, gx = xp - 2;
            float v0 = 0.f, v1 = 0.f, v2 = 0.f;
            if (gy >= 0 && gy < 64 && gx >= 0 && gx < 64) {
                const float* xb = x + (size_t)n * 12288 + gy * 64 + gx;
                v0 = xb[0]; v1 = xb[4096]; v2 = xb[8192];
            }
            o[j * 4 + 0] = (_Float16)v0;
            o[j * 4 + 1] = (_Float16)v1;
            o[j * 4 + 2] = (_Float16)v2;
            o[j * 4 + 3] = (_Float16)0.f;
        }
        *(half8*)&X4P[(size_t)pp * 4] = o;
    } else if (b < 2640) {
        int idx = (b - 2380) * 256 + t;
        if (idx < 9216) {               // conv2: K=288, 1 group
            int j = idx & 7, co = (idx >> 3) & 31, k8 = idx >> 8;
            int k = k8 * 8 + j, tap = k >> 5, ci = k & 31;
            t2[idx] = (_Float16)w2[(size_t)(co * 32 + ci) * 9 + tap];
        } else if (idx < 27648) {       // conv3: 2 cout groups
            int e = idx - 9216;
            int j = e & 7, co = (e >> 3) & 31, r = e >> 8;
            int k8 = r % 36, gg = r / 36;
            int k = k8 * 8 + j, tap = k >> 5, ci = k & 31;
            t3[e] = (_Float16)w3[(size_t)((gg * 32 + co) * 32 + ci) * 9 + tap];
        } else if (idx < 64512) {       // conv4: 2 cout groups x 2 ci-chunks
            int e = idx - 27648;
            int j = e & 7, co = (e >> 3) & 31, r = e >> 8;
            int k8 = r % 36, gc = r / 36;
            int g = gc >> 1, cc = gc & 1;
            int kl = k8 * 8 + j, tap = kl >> 5, ci = cc * 32 + (kl & 31);
            t4[e] = (_Float16)w4[(size_t)((g * 32 + co) * 64 + ci) * 9 + tap];
        } else if (idx < 66560) {       // conv1: K=64 padded
            int e = idx - 64512;
            int j = e & 7, co = (e >> 3) & 31, k8 = e >> 8;
            int k = k8 * 8 + j, tap = k >> 2, ci = k & 3;
            t1[e] = (_Float16)((tap < 9 && ci < 3) ? w1[(size_t)(co * 3 + ci) * 9 + tap] : 0.f);
        }
    } else if (b < 3152) {
        __shared__ float lds[64][65];
        int b2 = b - 2640;
        const int yx0 = (b2 & 3) * 64;
        const int j = b2 >> 2;
        #pragma unroll
        for (int i = 0; i < 16; ++i) {
            int idx = t + 256 * i;
            int c = idx >> 6, yxl = idx & 63;
            lds[c][yxl] = f1w[(size_t)j * 16384 + c * 256 + yx0 + yxl];
        }
        __syncthreads();
        #pragma unroll
        for (int i = 0; i < 2; ++i) {
            int idx = t + 256 * i;
            int yxl = idx >> 3, c8 = idx & 7;
            half8 h;
            #pragma unroll
            for (int jj = 0; jj < 8; ++jj)
                h[jj] = (_Float16)lds[c8 * 8 + jj][yxl];
            *(half8*)&w1t[(size_t)j * 16384 + (size_t)(yx0 + yxl) * 64 + c8 * 8] = h;
        }
    } else {
        if (t < 60) {
            float phi = qw[t * 3], th = qw[t * 3 + 1], om = qw[t * 3 + 2];
            float c = cosf(0.5f * th), s = sinf(0.5f * th);
            float apo = 0.5f * (phi + om), amo = 0.5f * (phi - om);
            float cpo = cosf(apo), spo = sinf(apo);
            float cmo = cosf(amo), smo = sinf(amo);
            rotm[t * 8 + 0] = cpo * c;  rotm[t * 8 + 1] = -spo * c;
            rotm[t * 8 + 2] = -cmo * s; rotm[t * 8 + 3] = -smo * s;
            rotm[t * 8 + 4] = cmo * s;  rotm[t * 8 + 5] = -smo * s;
            rotm[t * 8 + 6] = cpo * c;  rotm[t * 8 + 7] = spo * c;
        }
        for (int e = t; e < 6144; e += 256) {
            int layer = e >> 10, i = e & 1023;
            int r = layer % 9 + 1;
            int jdx = i;
            for (int w = 9; w >= 0; --w) {
                int tt = (w + r) % 10;
                int pc = 9 - w, pt_ = 9 - tt;
                jdx ^= ((jdx >> pc) & 1) << pt_;
            }
            perm[e] = (unsigned short)jdx;
        }
    }
}

// ---------------------------------------------------------------------------
// conv1: conv1 via MFMA from X4P -> Yg = fp16(conv1+bias) NHWC (256,64,64,32)
// + BN1 partials. Y packed through LDS for coalesced half8 stores.
// ---------------------------------------------------------------------------
__global__ __launch_bounds__(256) void conv1_stats_kernel(
    const _Float16* __restrict__ X4P, const _Float16* __restrict__ w1m,
    const float* __restrict__ bias, _Float16* __restrict__ Yg,
    float* __restrict__ partials)
{
    constexpr int TC = 66, TR = 6;
    constexpr int NPIX = (TR + 1) * TC;     // 462
    __shared__ __align__(16) _Float16 s_in[NPIX * 4];
    __shared__ __align__(16) _Float16 s_w[2048];
    __shared__ __align__(16) _Float16 s_y[256 * 32];   // 16 KB
    __shared__ float s_red[64];

    const int t = threadIdx.x;
    const int row0 = blockIdx.x * 4;
    const int n = blockIdx.z;

    *(half8*)&s_w[t * 8] = *(const half8*)&w1m[t * 8];

    for (int p = t; p < NPIX; p += 256) {
        int col = p % TC, r = p / TC;
        uint2 u = make_uint2(0u, 0u);
        if (r < TR) {
            size_t pb = ((size_t)(n * 70 + row0 + r + 1) * 68 + col + 1) * 4;
            u = *(const uint2*)&X4P[pb];
        }
        *(uint2*)&s_in[p * 4] = u;
    }
    if (t < 64) s_red[t] = 0.f;
    __syncthreads();

    const int w = t >> 6, l = t & 63;
    const int lm = l & 15, lg = l >> 4;
    int pA[4];
    #pragma unroll
    for (int f = 0; f < 4; ++f) {
        int m = w * 64 + f * 16 + lm;
        pA[f] = (m >> 6) * TC + (m & 63);
    }
    f32x4 zero4 = {0.f, 0.f, 0.f, 0.f};
    f32x4 acc[4][2];
    #pragma unroll
    for (int f = 0; f < 4; ++f) { acc[f][0] = zero4; acc[f][1] = zero4; }

    {
        const int t0 = lg * 2;
        const int off0 = (t0 / 3) * TC + (t0 % 3);
        const int off1 = ((t0 + 1) / 3) * TC + ((t0 + 1) % 3);
        half8 b0 = *(const half8*)&s_w[(lg * 32 + lm) * 8];
        half8 b1 = *(const half8*)&s_w[(lg * 32 + 16 + lm) * 8];
        #pragma unroll
        for (int f = 0; f < 4; ++f) {
            half4 alo = *(const half4*)&s_in[(pA[f] + off0) * 4];
            half4 ahi = *(const half4*)&s_in[(pA[f] + off1) * 4];
            half8 a;
            #pragma unroll
            for (int j = 0; j < 4; ++j) { a[j] = alo[j]; a[4 + j] = ahi[j]; }
            acc[f][0] = __builtin_amdgcn_mfma_f32_16x16x32_f16(a, b0, acc[f][0], 0, 0, 0);
            acc[f][1] = __builtin_amdgcn_mfma_f32_16x16x32_f16(a, b1, acc[f][1], 0, 0, 0);
        }
    }
    {
        half8 b0 = *(const half8*)&s_w[((4 + lg) * 32 + lm) * 8];
        half8 b1 = *(const half8*)&s_w[((4 + lg) * 32 + 16 + lm) * 8];
        #pragma unroll
        for (int f = 0; f < 4; ++f) {
            half8 a;
            #pragma unroll
            for (int j = 0; j < 8; ++j) a[j] = (_Float16)0.f;
            if (lg == 0) {
                half4 alo = *(const half4*)&s_in[(pA[f] + 134) * 4];
                half4 ahi = *(const half4*)&s_in[(pA[f] + 198) * 4];
                #pragma unroll
                for (int j = 0; j < 4; ++j) { a[j] = alo[j]; a[4 + j] = ahi[j]; }
            }
            acc[f][0] = __builtin_amdgcn_mfma_f32_16x16x32_f16(a, b0, acc[f][0], 0, 0, 0);
            acc[f][1] = __builtin_amdgcn_mfma_f32_16x16x32_f16(a, b1, acc[f][1], 0, 0, 0);
        }
    }

    float bv0 = bias[lm];
    float bv1 = bias[16 + lm];
    float s0 = 0.f, s20 = 0.f, s1 = 0.f, s21 = 0.f;
    #pragma unroll
    for (int f = 0; f < 4; ++f) {
        #pragma unroll
        for (int r = 0; r < 4; ++r) {
            float v0 = acc[f][0][r] + bv0;
            float v1 = acc[f][1][r] + bv1;
            int p_loc = w * 64 + f * 16 + lg * 4 + r;
            s_y[p_loc * 32 + lm] = (_Float16)v0;
            s_y[p_loc * 32 + 16 + lm] = (_Float16)v1;
            s0 += v0; s20 += v0 * v0;
            s1 += v1; s21 += v1 * v1;
        }
    }
    s0 += __shfl_xor(s0, 16);  s0 += __shfl_xor(s0, 32);
    s1 += __shfl_xor(s1, 16);  s1 += __shfl_xor(s1, 32);
    s20 += __shfl_xor(s20, 16); s20 += __shfl_xor(s20, 32);
    s21 += __shfl_xor(s21, 16); s21 += __shfl_xor(s21, 32);
    if (l < 16) {
        atomicAdd(&s_red[lm], s0);
        atomicAdd(&s_red[16 + lm], s1);
        atomicAdd(&s_red[32 + lm], s20);
        atomicAdd(&s_red[48 + lm], s21);
    }
    __syncthreads();

    // coalesced Y store: 4 rows x 64 cols x 32 ch contiguous
    {
        _Float16* Yb = Yg + ((size_t)(n * 64 + row0) * 64) * 32;
        #pragma unroll
        for (int i = 0; i < 4; ++i) {
            int idx = t + 256 * i;
            *(half8*)&Yb[(size_t)idx * 8] = *(const half8*)&s_y[idx * 8];
        }
    }
    if (t < 64)
        partials[((size_t)n * 16 + blockIdx.x) * 64 + t] = s_red[t];
}

// ---------------------------------------------------------------------------
// conv2 FUSED v8: channel-slice-major LDS layout [4 k-slices][660 px][8 ch]
// (conv3-style) -> single ds_read_b128 per A-fragment, conflict-free reads
// AND writes. Stages bn1(Yg)+relu from global at load. LDS 42.5 KB,
// 3 blocks/CU. 512 thr, ROWS=8; grid (8,1,256).
// ---------------------------------------------------------------------------
__global__ __launch_bounds__(512, 6) void conv2_fused_kernel(
    const _Float16* __restrict__ Yg, const _Float16* __restrict__ ssh1,
    const _Float16* __restrict__ wt2, const float* __restrict__ c2bias,
    _Float16* __restrict__ out0, _Float16* __restrict__ out1,
    float* __restrict__ partials)
{
    constexpr int COUT = 32, MF = 4, NB = 2;
    constexpr int ROWS = 8;
    constexpr int TC = 66, NPIX = 10 * 66;         // 660
    __shared__ __align__(16) _Float16 s_in[NPIX * 32];   // 42,240 B
    __shared__ float s_red[64];

    const int t = threadIdx.x;
    const int row0 = blockIdx.x * ROWS;
    const int n = blockIdx.z;
    const int w = t >> 6, l = t & 63;
    const int lm = l & 15, lg = l >> 4;

    if (t < 64) s_red[t] = 0.f;

    // ---- stage relu(bn1(Y)) tile, p-fastest: conflict-free b128 writes ----
    for (int idx = t; idx < NPIX * 4; idx += 512) {
        int c8 = idx / NPIX;
        int p = idx - c8 * NPIX;
        int py = p / 66, px = p - py * 66;
        int gy = row0 - 1 + py, gx = px - 1;
        half8 v;
        #pragma unroll
        for (int j = 0; j < 8; ++j) v[j] = (_Float16)0.f;
        if (gy >= 0 && gy < 64 && gx >= 0 && gx < 64) {
            half8 y = *(const half8*)&Yg[(((size_t)n * 64 + gy) * 64 + gx) * 32 + c8 * 8];
            half8 sc = *(const half8*)&ssh1[c8 * 8];
            half8 sh = *(const half8*)&ssh1[32 + c8 * 8];
            #pragma unroll
            for (int j = 0; j < 8; ++j) {
                _Float16 f = y[j] * sc[j] + sh[j];
                v[j] = f > (_Float16)0.f ? f : (_Float16)0.f;
            }
        }
        *(half8*)&s_in[(c8 * NPIX + p) * 8] = v;
    }
    __syncthreads();

    // ---- conv2 main compute: wave = output row (row0+w), columns f*16+lm ----
    int pA[MF];
    #pragma unroll
    for (int f = 0; f < MF; ++f)
        pA[f] = w * TC + f * 16 + lm;
    f32x4 zero4 = {0.f, 0.f, 0.f, 0.f};
    f32x4 acc[MF][NB];
    #pragma unroll
    for (int f = 0; f < MF; ++f)
        #pragma unroll
        for (int nb = 0; nb < NB; ++nb) acc[f][nb] = zero4;

    #pragma unroll
    for (int tap = 0; tap < 9; ++tap) {
        const int dy = tap / 3, dx = tap % 3;
        const int poff = dy * TC + dx;
        half8 b[NB];
        #pragma unroll
        for (int nb = 0; nb < NB; ++nb) {
            int col = nb * 16 + lm;
            b[nb] = *(const half8*)&wt2[((tap * 4 + lg) * 32 + col) * 8];
        }
        #pragma unroll
        for (int f = 0; f < MF; ++f) {
            int p = pA[f] + poff;
            half8 a = *(const half8*)&s_in[(lg * NPIX + p) * 8];
            #pragma unroll
            for (int nb = 0; nb < NB; ++nb)
                acc[f][nb] = __builtin_amdgcn_mfma_f32_16x16x32_f16(a, b[nb], acc[f][nb], 0, 0, 0);
        }
    }

    // ---- bias fold + stats (registers only) ----
    float bv[NB], s[NB], s2[NB];
    #pragma unroll
    for (int nb = 0; nb < NB; ++nb) {
        bv[nb] = c2bias[nb * 16 + lm];
        s[nb] = 0.f; s2[nb] = 0.f;
    }
    #pragma unroll
    for (int f = 0; f < MF; ++f) {
        #pragma unroll
        for (int nb = 0; nb < NB; ++nb) {
            #pragma unroll
            for (int r = 0; r < 4; ++r) {
                float v = acc[f][nb][r] + bv[nb];
                acc[f][nb][r] = v;
                s[nb] += v; s2[nb] += v * v;
            }
        }
    }
    #pragma unroll
    for (int nb = 0; nb < NB; ++nb) {
        s[nb] += __shfl_xor(s[nb], 16);  s[nb] += __shfl_xor(s[nb], 32);
        s2[nb] += __shfl_xor(s2[nb], 16); s2[nb] += __shfl_xor(s2[nb], 32);
    }
    if (l < 16) {
        #pragma unroll
        for (int nb = 0; nb < NB; ++nb) {
            atomicAdd(&s_red[nb * 16 + lm], s[nb]);
            atomicAdd(&s_red[32 + nb * 16 + lm], s2[nb]);
        }
    }

    // ---- pool: h-pool in lane -> pk rows -> vertical gather -> stores ----
    {
        __syncthreads();                    // all MFMA reads of s_in done
        _Float16* pk = s_in;                // [8 rows][32 xp][32 ch] min, +8192 max
        #pragma unroll
        for (int nb = 0; nb < NB; ++nb) {
            #pragma unroll
            for (int f = 0; f < MF; ++f) {
                float v0 = acc[f][nb][0], v1 = acc[f][nb][1];
                float v2 = acc[f][nb][2], v3 = acc[f][nb][3];
                int xp0 = f * 8 + lg * 2;
                int o0 = (w * 32 + xp0) * COUT + nb * 16 + lm;
                int o1 = (w * 32 + xp0 + 1) * COUT + nb * 16 + lm;
                pk[o0] = (_Float16)fminf(v0, v1);
                pk[8192 + o0] = (_Float16)fmaxf(v0, v1);
                pk[o1] = (_Float16)fminf(v2, v3);
                pk[8192 + o1] = (_Float16)fmaxf(v2, v3);
            }
        }
        __syncthreads();
        // vertical gather: 4 pooled rows x 32 xp x 4 c8 = 512 threads
        int hp_row = t >> 7, rem = t & 127;
        int xp = rem >> 2, c8 = rem & 3;
        half8 mnA = *(const half8*)&pk[((2 * hp_row) * 32 + xp) * COUT + c8 * 8];
        half8 mnB = *(const half8*)&pk[((2 * hp_row + 1) * 32 + xp) * COUT + c8 * 8];
        half8 mxA = *(const half8*)&pk[8192 + ((2 * hp_row) * 32 + xp) * COUT + c8 * 8];
        half8 mxB = *(const half8*)&pk[8192 + ((2 * hp_row + 1) * 32 + xp) * COUT + c8 * 8];
        half8 mn, mx;
        #pragma unroll
        for (int j = 0; j < 8; ++j) {
            mn[j] = mnA[j] < mnB[j] ? mnA[j] : mnB[j];
            mx[j] = mxA[j] > mxB[j] ? mxA[j] : mxB[j];
        }
        size_t ob = (((size_t)n * 32 + (row0 >> 1) + hp_row) * 32 + xp) * COUT + c8 * 8;
        *(half8*)&out0[ob] = mn;
        *(half8*)&out1[ob] = mx;
    }

    __syncthreads();
    if (t < 64) {
        size_t bid = (size_t)n * gridDim.x + blockIdx.x;
        partials[bid * 64 + t] = s_red[t];
    }
}

// ---------------------------------------------------------------------------
// Implicit-GEMM 3x3 conv via MFMA (single-pass staging). Used for conv3/conv4.
// ---------------------------------------------------------------------------
template<int BLOCK, int W, int CIN, int COUT, int MF, int NB,
         bool MMIN, bool POOL>
__global__ __launch_bounds__(BLOCK, (BLOCK == 512 ? 4 : 3)) void conv_mfma_kernel(
    const _Float16* __restrict__ in0, const _Float16* __restrict__ in1,
    const _Float16* __restrict__ coef, const _Float16* __restrict__ wt,
    const float* __restrict__ bias,
    _Float16* __restrict__ out0, _Float16* __restrict__ out1,
    float* __restrict__ partials)
{
    constexpr int H = W;
    constexpr int NWAVE = BLOCK / 64;
    constexpr int SPW = MF * 16;
    constexpr int ROWS = NWAVE * SPW / W;
    constexpr int TR = ROWS + 2;
    constexpr int TC = W + 2;
    constexpr int NPIX = TR * TC;
    constexpr int NCH = CIN / 32;
    constexpr int C8N = CIN / 8;
    constexpr int KC = 288;
    constexpr int COUTB = NB * 16;
    __shared__ __align__(16) _Float16 s_in[NPIX * CIN];
    __shared__ float s_red[2 * COUTB];

    const int t = threadIdx.x;
    const int row0 = blockIdx.x * ROWS;
    const int n = blockIdx.z;

    const int w = t >> 6, l = t & 63;
    const int lm = l & 15, lg = l >> 4;
    int pA[MF];
    #pragma unroll
    for (int f = 0; f < MF; ++f) {
        int m = w * SPW + f * 16 + lm;
        pA[f] = (m / W) * TC + (m % W);
    }
    f32x4 zero4 = {0.f, 0.f, 0.f, 0.f};
    f32x4 acc[MF][NB];
    #pragma unroll
    for (int f = 0; f < MF; ++f)
        #pragma unroll
        for (int nb = 0; nb < NB; ++nb) acc[f][nb] = zero4;
    if (t < 2 * COUTB) s_red[t] = 0.f;

    for (int idx = t; idx < NPIX * C8N; idx += BLOCK) {
        int c8 = idx % C8N;
        int p = idx / C8N;
        int col = p % TC, r = p / TC;
        int gy = row0 + r - 1, gx = col - 1;
        half8 v;
        #pragma unroll
        for (int j = 0; j < 8; ++j) v[j] = (_Float16)0.f;
        if (gy >= 0 && gy < H && gx >= 0 && gx < W) {
            size_t gidx = (((size_t)n * H + gy) * W + gx) * CIN + c8 * 8;
            if (MMIN) {
                half8 mn = *(const half8*)&in0[gidx];
                half8 mx = *(const half8*)&in1[gidx];
                half8 sa = *(const half8*)&coef[c8 * 8];
                half8 sb = *(const half8*)&coef[CIN + c8 * 8];
                half8 sh = *(const half8*)&coef[2 * CIN + c8 * 8];
                #pragma unroll
                for (int j = 0; j < 8; ++j) {
                    _Float16 f = mx[j] * sa[j] + mn[j] * sb[j] + sh[j];
                    v[j] = f > (_Float16)0.f ? f : (_Float16)0.f;
                }
            } else {
                v = *(const half8*)&in0[gidx];
                if (coef) {
                    half8 sc = *(const half8*)&coef[c8 * 8];
                    half8 sh = *(const half8*)&coef[CIN + c8 * 8];
                    #pragma unroll
                    for (int j = 0; j < 8; ++j) {
                        _Float16 f = v[j] * sc[j] + sh[j];
                        v[j] = f > (_Float16)0.f ? f : (_Float16)0.f;
                    }
                }
            }
        }
        *(half8*)&s_in[(c8 * NPIX + p) * 8] = v;
    }
    __syncthreads();

    #pragma unroll
    for (int tap = 0; tap < 9; ++tap) {
        const int dy = tap / 3, dx = tap % 3;
        const int poff = dy * TC + dx;
        #pragma unroll
        for (int cc = 0; cc < NCH; ++cc) {
            half8 b[NB];
            #pragma unroll
            for (int nb = 0; nb < NB; ++nb) {
                int cog = nb * 16 + lm;
                int gg = cog >> 5, col = cog & 31;
                const _Float16* wp = wt + (size_t)(gg * NCH + cc) * KC * 32;
                b[nb] = *(const half8*)&wp[((tap * 4 + lg) * 32 + col) * 8];
            }
            #pragma unroll
            for (int f = 0; f < MF; ++f) {
                half8 a = *(const half8*)&s_in[((cc * 4 + lg) * NPIX + pA[f] + poff) * 8];
                #pragma unroll
                for (int nb = 0; nb < NB; ++nb)
                    acc[f][nb] = __builtin_amdgcn_mfma_f32_16x16x32_f16(a, b[nb], acc[f][nb], 0, 0, 0);
            }
        }
    }

    float bv[NB], s[NB], s2[NB];
    #pragma unroll
    for (int nb = 0; nb < NB; ++nb) {
        bv[nb] = bias[nb * 16 + lm];
        s[nb] = 0.f; s2[nb] = 0.f;
    }
    #pragma unroll
    for (int f = 0; f < MF; ++f) {
        #pragma unroll
        for (int r = 0; r < 4; ++r) {
            int m = w * SPW + f * 16 + lg * 4 + r;
            int yy = row0 + m / W, xo = m % W;
            size_t base = (((size_t)n * H + yy) * W + xo) * COUT;
            #pragma unroll
            for (int nb = 0; nb < NB; ++nb) {
                float v = acc[f][nb][r] + bv[nb];
                if (!POOL) out0[base + nb * 16 + lm] = (_Float16)v;
                s[nb] += v; s2[nb] += v * v;
            }
        }
    }
    #pragma unroll
    for (int nb = 0; nb < NB; ++nb) {
        s[nb] += __shfl_xor(s[nb], 16);  s[nb] += __shfl_xor(s[nb], 32);
        s2[nb] += __shfl_xor(s2[nb], 16); s2[nb] += __shfl_xor(s2[nb], 32);
    }
    if (l < 16) {
        #pragma unroll
        for (int nb = 0; nb < NB; ++nb) {
            atomicAdd(&s_red[nb * 16 + lm], s[nb]);
            atomicAdd(&s_red[COUTB + nb * 16 + lm], s2[nb]);
        }
    }

    if (POOL) {
        constexpr int FH = MF / 2;
        constexpr int PPIX = (ROWS / 2) * (W / 2);
        static_assert(2 * PPIX * COUT <= NPIX * CIN, "pool pack fits in s_in");
        __syncthreads();
        _Float16* pk = s_in;
        #pragma unroll
        for (int nb = 0; nb < NB; ++nb) {
            #pragma unroll
            for (int f = 0; f < FH; ++f) {
                #pragma unroll
                for (int rp = 0; rp < 2; ++rp) {
                    float a0 = acc[f][nb][2 * rp] + bv[nb];
                    float a1 = acc[f][nb][2 * rp + 1] + bv[nb];
                    float a2 = acc[f + FH][nb][2 * rp] + bv[nb];
                    float a3 = acc[f + FH][nb][2 * rp + 1] + bv[nb];
                    float mn = fminf(fminf(a0, a1), fminf(a2, a3));
                    float mx = fmaxf(fmaxf(a0, a1), fmaxf(a2, a3));
                    int xp = f * 8 + lg * 2 + rp;
                    int o = (w * (W / 2) + xp) * COUT + nb * 16 + lm;
                    pk[o] = (_Float16)mn;
                    pk[PPIX * COUT + o] = (_Float16)mx;
                }
            }
        }
        __syncthreads();
        size_t gb = (((size_t)n * (H / 2) + (row0 >> 1)) * (W / 2)) * COUT;
        for (int idx = t; idx < PPIX * COUT / 8; idx += BLOCK) {
            *(half8*)&out0[gb + (size_t)idx * 8] = *(const half8*)&pk[idx * 8];
            *(half8*)&out1[gb + (size_t)idx * 8] = *(const half8*)&pk[(PPIX * COUT + idx * 8)];
        }
    }

    __syncthreads();
    if (t < 2 * COUTB) {
        size_t bid = (size_t)n * gridDim.x + blockIdx.x;
        partials[bid * 2 * COUTB + t] = s_red[t];
    }
}

// ---------------------------------------------------------------------------
// Reduce per-block partials -> BN coefficients. Record = [sum C | sumsq C].
// ---------------------------------------------------------------------------
__global__ __launch_bounds__(256) void bn_finalize_kernel(
    const float* __restrict__ partials, int nx, float inv_count,
    const float* __restrict__ gamma, const float* __restrict__ beta,
    float* __restrict__ ss, _Float16* __restrict__ ssh,
    _Float16* __restrict__ sab, int COUT)
{
    const int c = blockIdx.x;
    const int t = threadIdx.x;
    float sum = 0.f, sq = 0.f;
    int total = 256 * nx;
    for (int e = t; e < total; e += 256) {
        size_t off = (size_t)e * 2 * COUT;
        sum += partials[off + c];
        sq  += partials[off + COUT + c];
    }
    #pragma unroll
    for (int off = 32; off > 0; off >>= 1) {
        sum += __shfl_xor(sum, off);
        sq  += __shfl_xor(sq, off);
    }
    __shared__ float rs[4], rq[4];
    if ((t & 63) == 0) { rs[t >> 6] = sum; rq[t >> 6] = sq; }
    __syncthreads();
    if (t == 0) {
        sum = rs[0] + rs[1] + rs[2] + rs[3];
        sq  = rq[0] + rq[1] + rq[2] + rq[3];
        float mean = sum * inv_count;
        float var = sq * inv_count - mean * mean;
        float scale = gamma[c] * rsqrtf(var + 1e-5f);
        float shift = beta[c] - mean * scale;
        ss[c] = scale;
        ss[COUT + c] = shift;
        if (ssh) {
            ssh[c] = (_Float16)scale;
            ssh[COUT + c] = (_Float16)shift;
        }
        if (sab) {
            sab[c] = (_Float16)(scale > 0.f ? scale : 0.f);
            sab[COUT + c] = (_Float16)(scale > 0.f ? 0.f : scale);
            sab[2 * COUT + c] = (_Float16)shift;
        }
    }
}

// ---------------------------------------------------------------------------
// fc1 MFMA GEMM (K-split): A = relu(bn4(pooled minmax pair)) on the fly.
// ---------------------------------------------------------------------------
__global__ __launch_bounds__(256) void fc1_mfma_kernel(
    const _Float16* __restrict__ Amin, const _Float16* __restrict__ Amax,
    const _Float16* __restrict__ sab, const _Float16* __restrict__ Bw,
    float* __restrict__ hp)
{
    __shared__ __align__(16) _Float16 As[64][72];
    __shared__ __align__(16) _Float16 Bs[128][72];
    const int t = threadIdx.x;
    const int mt = blockIdx.x;
    const int kc = blockIdx.y;
    const int w = t >> 6, l = t & 63;
    const int lm = l & 15, lg = l >> 4;

    f32x4 zero4 = {0.f, 0.f, 0.f, 0.f};
    f32x4 acc[8];
    #pragma unroll
    for (int nb = 0; nb < 8; ++nb) acc[nb] = zero4;

    const size_t a_base = (size_t)(mt * 64) * 16384 + (size_t)kc * 512;
    const size_t b_base = (size_t)kc * 512;

    for (int p = 0; p < 8; ++p) {
        __syncthreads();
        #pragma unroll
        for (int i = 0; i < 2; ++i) {
            int idx = t + 256 * i;
            int r = idx >> 3, c8 = idx & 7;
            size_t off = a_base + (size_t)r * 16384 + p * 64 + c8 * 8;
            half8 mn = *(const half8*)&Amin[off];
            half8 mx = *(const half8*)&Amax[off];
            half8 sa = *(const half8*)&sab[c8 * 8];
            half8 sb = *(const half8*)&sab[64 + c8 * 8];
            half8 sh = *(const half8*)&sab[128 + c8 * 8];
            half8 v;
            #pragma unroll
            for (int j = 0; j < 8; ++j) {
                _Float16 f = mx[j] * sa[j] + mn[j] * sb[j] + sh[j];
                v[j] = f > (_Float16)0.f ? f : (_Float16)0.f;
            }
            *(half8*)&As[r][c8 * 8] = v;
        }
        #pragma unroll
        for (int i = 0; i < 4; ++i) {
            int idx = t + 256 * i;
            int r = idx >> 3, c8 = idx & 7;
            *(half8*)&Bs[r][c8 * 8] =
                *(const half8*)&Bw[b_base + (size_t)r * 16384 + p * 64 + c8 * 8];
        }
        __syncthreads();
        #pragma unroll
        for (int ks = 0; ks < 64; ks += 32) {
            half8 a = *(const half8*)&As[w * 16 + lm][ks + lg * 8];
            #pragma unroll
            for (int nb = 0; nb < 8; ++nb) {
                half8 b = *(const half8*)&Bs[nb * 16 + lm][ks + lg * 8];
                acc[nb] = __builtin_amdgcn_mfma_f32_16x16x32_f16(a, b, acc[nb], 0, 0, 0);
            }
        }
    }
    #pragma unroll
    for (int nb = 0; nb < 8; ++nb) {
        #pragma unroll
        for (int r = 0; r < 4; ++r) {
            int row = mt * 64 + w * 16 + lg * 4 + r;
            hp[((size_t)kc * 256 + row) * 128 + nb * 16 + lm] = acc[nb][r];
        }
    }
}

// ---------------------------------------------------------------------------
// fc1 reduce + relu + fc2 + quantum circuit + head, one block per batch n.
// 256 threads = 4 waves; quantum state spread over 4 waves (4 amps/lane):
// amp = (r<<8)|(wv<<6)|lane. Gates: bits 8-9 in-register, bits 6-7 LDS
// cross-wave exchange, bits 0-5 shfl_xor.
// ---------------------------------------------------------------------------
__global__ __launch_bounds__(256) void fcq_kernel(
    const float* __restrict__ hp, const float* __restrict__ f1b,
    const float* __restrict__ f2w, const float* __restrict__ f2b,
    const float* __restrict__ rotm, const unsigned short* __restrict__ perm,
    const float* __restrict__ head_w, const float* __restrict__ head_b,
    float* __restrict__ outp)
{
    __shared__ float lre[1024];
    __shared__ float lim[1024];
    __shared__ float hl[128];
    __shared__ float xql[10];
    const int n = blockIdx.x;
    const int t = threadIdx.x;
    const int l = t & 63;
    const int wv = t >> 6;

    // ---- fc1 reduce + bias + relu (exact original order, t<128) ----
    if (t < 128) {
        float s = f1b[t];
        #pragma unroll
        for (int kc = 0; kc < 32; ++kc) s += hp[((size_t)kc * 256 + n) * 128 + t];
        hl[t] = fmaxf(0.f, s);
    }
    __syncthreads();
    // ---- fc2 ----
    if (t < 10) {
        float o = f2b[t];
        #pragma unroll 4
        for (int k = 0; k < 128; ++k) o += f2w[t * 128 + k] * hl[k];
        xql[t] = o;
    }
    __syncthreads();

    // ---- quantum: 4 amps/lane, amp = (r<<8)|(wv<<6)|l ----
    const int ampb = (wv << 6) | l;          // low 8 bits of amp (r adds <<8)
    float ar[4], ai[4];
    #pragma unroll
    for (int r = 0; r < 4; ++r) { ar[r] = 0.f; ai[r] = 0.f; }
    if (t == 0) ar[0] = 1.f;

    // RY embedding layer (real amplitudes)
    #pragma unroll
    for (int w = 0; w < 10; ++w) {
        float th = 0.5f * PI_F * xql[w];
        float c = cosf(th), s = sinf(th);
        const int k = 9 - w;
        if (k >= 8) {
            const int b = k - 8;
            #pragma unroll
            for (int r = 0; r < 4; ++r) {
                if (!(r & (1 << b))) {
                    int r1 = r | (1 << b);
                    float a0 = ar[r], a1 = ar[r1];
                    ar[r]  = c * a0 - s * a1;
                    ar[r1] = s * a0 + c * a1;
                }
            }
        } else if (k >= 6) {
            #pragma unroll
            for (int r = 0; r < 4; ++r) lre[(r << 8) | ampb] = ar[r];
            __syncthreads();
            float ss = ((wv >> (k - 6)) & 1) ? s : -s;
            #pragma unroll
            for (int r = 0; r < 4; ++r) {
                float p = lre[((r << 8) | ampb) ^ (1 << k)];
                ar[r] = c * ar[r] + ss * p;
            }
            __syncthreads();
        } else {
            float ss = ((l >> k) & 1) ? s : -s;
            #pragma unroll
            for (int r = 0; r < 4; ++r) {
                float p = __shfl_xor(ar[r], 1 << k);
                ar[r] = c * ar[r] + ss * p;
            }
        }
    }

    #pragma unroll 1
    for (int layer = 0; layer < 6; ++layer) {
        #pragma unroll
        for (int w = 0; w < 10; ++w) {
            const float* m = rotm + (layer * 10 + w) * 8;
            float m00r = m[0], m00i = m[1], m01r = m[2], m01i = m[3];
            float m10r = m[4], m10i = m[5], m11r = m[6], m11i = m[7];
            const int k = 9 - w;
            if (k >= 8) {
                const int b = k - 8;
                #pragma unroll
                for (int r = 0; r < 4; ++r) {
                    if (!(r & (1 << b))) {
                        int r1 = r | (1 << b);
                        float a0r = ar[r], a0i = ai[r];
                        float a1r = ar[r1], a1i = ai[r1];
                        ar[r]  = m00r * a0r - m00i * a0i + m01r * a1r - m01i * a1i;
                        ai[r]  = m00r * a0i + m00i * a0r + m01r * a1i + m01i * a1r;
                        ar[r1] = m10r * a0r - m10i * a0i + m11r * a1r - m11i * a1i;
                        ai[r1] = m10r * a0i + m10i * a0r + m11r * a1i + m11i * a1r;
                    }
                }
            } else if (k >= 6) {
                #pragma unroll
                for (int r = 0; r < 4; ++r) {
                    lre[(r << 8) | ampb] = ar[r];
                    lim[(r << 8) | ampb] = ai[r];
                }
                __syncthreads();
                int bit = (wv >> (k - 6)) & 1;
                float mAr = bit ? m11r : m00r, mAi = bit ? m11i : m00i;
                float mBr = bit ? m10r : m01r, mBi = bit ? m10i : m01i;
                #pragma unroll
                for (int r = 0; r < 4; ++r) {
                    int pa = ((r << 8) | ampb) ^ (1 << k);
                    float pr = lre[pa], pi = lim[pa];
                    float mr = ar[r], mi = ai[r];
                    ar[r] = mAr * mr - mAi * mi + mBr * pr - mBi * pi;
                    ai[r] = mAr * mi + mAi * mr + mBr * pi + mBi * pr;
                }
                __syncthreads();
            } else {
                int bit = (l >> k) & 1;
                float mAr = bit ? m11r : m00r, mAi = bit ? m11i : m00i;
                float mBr = bit ? m10r : m01r, mBi = bit ? m10i : m01i;
                #pragma unroll
                for (int r = 0; r < 4; ++r) {
                    float pr = __shfl_xor(ar[r], 1 << k);
                    float pi = __shfl_xor(ai[r], 1 << k);
                    float mr = ar[r], mi = ai[r];
                    ar[r] = mAr * mr - mAi * mi + mBr * pr - mBi * pi;
                    ai[r] = mAr * mi + mAi * mr + mBr * pi + mBi * pr;
                }
            }
        }
        // layer permutation
        #pragma unroll
        for (int r = 0; r < 4; ++r) {
            lre[(r << 8) | ampb] = ar[r];
            lim[(r << 8) | ampb] = ai[r];
        }
        __syncthreads();
        const unsigned short* pt = perm + layer * 1024;
        #pragma unroll
        for (int r = 0; r < 4; ++r) {
            int ji = pt[(r << 8) | ampb];
            ar[r] = lre[ji];
            ai[r] = lim[ji];
        }
        __syncthreads();
    }

    // ---- Z expectations + head ----
    float S = 0.f, T9 = 0.f, T8 = 0.f;
    #pragma unroll
    for (int r = 0; r < 4; ++r) {
        float pr = ar[r] * ar[r] + ai[r] * ai[r];
        S += pr;
        T9 += (r & 2) ? -pr : pr;       // amp bit9 -> wire 0
        T8 += (r & 1) ? -pr : pr;       // amp bit8 -> wire 1
    }
    float pk[10];
    pk[0] = T9;
    pk[1] = T8;
    pk[2] = ((wv >> 1) & 1) ? -S : S;   // amp bit7 -> wire 2
    pk[3] = (wv & 1) ? -S : S;          // amp bit6 -> wire 3
    #pragma unroll
    for (int w = 4; w < 10; ++w)
        pk[w] = ((l >> (9 - w)) & 1) ? -S : S;
    #pragma unroll
    for (int w = 0; w < 10; ++w) {
        #pragma unroll
        for (int off = 1; off < 64; off <<= 1)
            pk[w] += __shfl_xor(pk[w], off);
    }
    if (l == 0) {
        #pragma unroll
        for (int w = 0; w < 10; ++w) lre[wv * 16 + w] = pk[w];
    }
    __syncthreads();
    if (t < 10) {
        float tot = lre[t] + lre[16 + t] + lre[32 + t] + lre[48 + t];
        lre[64 + t] = tot;
    }
    __syncthreads();
    if (t < 10) {
        float o = head_b[t];
        #pragma unroll
        for (int kk = 0; kk < 10; ++kk) o += lre[64 + kk] * head_w[t * 10 + kk];
        outp[n * 10 + t] = o;
    }
}

// ---------------------------------------------------------------------------
extern "C" void kernel_launch(void* const* d_in, const int* in_sizes, int n_in,
                              void* d_out, int out_size, void* d_ws, size_t ws_size,
                              hipStream_t stream)
{
    const float* x   = (const float*)d_in[0];
    const float* c1w = (const float*)d_in[1];  const float* c1b = (const float*)d_in[2];
    const float* g1  = (const float*)d_in[3];  const float* b1  = (const float*)d_in[4];
    const float* c2w = (const float*)d_in[5];  const float* c2b = (const float*)d_in[6];
    const float* g2  = (const float*)d_in[7];  const float* b2  = (const float*)d_in[8];
    const float* c3w = (const float*)d_in[9];  const float* c3b = (const float*)d_in[10];
    const float* g3  = (const float*)d_in[11]; const float* b3  = (const float*)d_in[12];
    const float* c4w = (const float*)d_in[13]; const float* c4b = (const float*)d_in[14];
    const float* g4  = (const float*)d_in[15]; const float* b4  = (const float*)d_in[16];
    const float* f1w = (const float*)d_in[17]; const float* f1b = (const float*)d_in[18];
    const float* f2w = (const float*)d_in[19]; const float* f2b = (const float*)d_in[20];
    const float* qw  = (const float*)d_in[21];
    const float* hw  = (const float*)d_in[22]; const float* hb  = (const float*)d_in[23];

    float* ws = (float*)d_ws;
    _Float16* H0 = (_Float16*)ws;              // 33,554,432 halves (67 MB)
    _Float16* H1 = H0 + 33554432;              // 33,554,432 halves (67 MB)
    float* part = ws + 33554432;               // 524,288
    float* ss1  = part + 524288;               // 64
    float* ss2  = ss1 + 64;                    // 64
    float* ss3  = ss2 + 64;                    // 128
    float* ss4  = ss3 + 128;                   // 128
    float* hp   = ss4 + 128;                   // 1,048,576
    float* rotm = hp + 1048576;                // 480
    unsigned short* perm16 = (unsigned short*)(rotm + 480);   // 6,144 u16
    _Float16* ssh1 = (_Float16*)(perm16 + 6144);   // 64 halves
    _Float16* ssh3 = ssh1 + 64;                // 128
    _Float16* sab2 = ssh3 + 128;               // 96
    _Float16* sab4 = sab2 + 96;                // 192
    _Float16* wt2  = sab4 + 192;               // 9,216
    _Float16* wt3  = wt2 + 9216;               // 18,432
    _Float16* wt4  = wt3 + 18432;              // 36,864
    _Float16* w1m  = wt4 + 36864;              // 2,048
    _Float16* w1t  = w1m + 2048;               // 2,097,152
    _Float16* X4P  = w1t + 2097152;            // 4,874,240 (256*70*68*4, 9.75 MB)

    // overlays (sequential lifetimes):
    //  Yg (conv1+bias fp16, 256x64x64x32 = 33.5M halves) = H0; dead once conv2
    //  completes; conv3 then writes its output into H0.
    _Float16* Yg    = H0;
    _Float16* minT2 = H1;                      // (256,32,32,32)
    _Float16* maxT2 = H1 + 8388608;
    _Float16* minT4 = H1;                      // (256,16,16,64)
    _Float16* maxT4 = H1 + 4194304;

    // unified one-time prep
    prep_kernel<<<3153, 256, 0, stream>>>(x, X4P, c1w, c2w, c3w, c4w,
                                          w1m, wt2, wt3, wt4, f1w, w1t,
                                          qw, rotm, perm16);

    // conv1: Y = fp16(conv1+bias) -> Yg (H0) + BN1 stats
    conv1_stats_kernel<<<dim3(16, 1, 256), 256, 0, stream>>>(
        X4P, w1m, c1b, Yg, part);
    bn_finalize_kernel<<<32, 256, 0, stream>>>(part, 16, 1.f / 1048576.f,
                                               g1, b1, ss1, ssh1, nullptr, 32);

    // conv2 FUSED v8 (channel-slice LDS layout): -> minT2/maxT2 + stats
    conv2_fused_kernel<<<dim3(8, 1, 256), 512, 0, stream>>>(
        Yg, ssh1, wt2, c2b, minT2, maxT2, part);
    bn_finalize_kernel<<<32, 256, 0, stream>>>(part, 8, 1.f / 1048576.f,
                                               g2, b2, ss2, nullptr, sab2, 32);

    // conv3 (512thr, 64 cout/wave, minmax input): relu(bn2(pool1)) -> H0
    conv_mfma_kernel<512, 32, 32, 64, 4, 4, true, false>
        <<<dim3(2, 1, 256), 512, 0, stream>>>(
        minT2, maxT2, sab2, wt3, c3b, H0, nullptr, part);
    bn_finalize_kernel<<<64, 256, 0, stream>>>(part, 2, 1.f / 262144.f,
                                               g3, b3, ss3, ssh3, nullptr, 64);

    // conv4 (512thr, single-pass CIN=64 staging, packed pooled stores)
    conv_mfma_kernel<512, 32, 64, 64, 4, 4, false, true>
        <<<dim3(2, 1, 256), 512, 0, stream>>>(
        H0, nullptr, ssh3, wt4, c4b, minT4, maxT4, part);
    bn_finalize_kernel<<<64, 256, 0, stream>>>(part, 2, 1.f / 262144.f,
                                               g4, b4, ss4, nullptr, sab4, 64);

    // fc1: MFMA GEMM with on-the-fly relu(bn4(pool2))
    fc1_mfma_kernel<<<dim3(4, 32), 256, 0, stream>>>(minT4, maxT4, sab4, w1t, hp);

    // fc1-reduce + fc2 + quantum circuit (4-wave) + head -> out (256,10)
    fcq_kernel<<<256, 256, 0, stream>>>(hp, f1b, f2w, f2b,
                                        rotm, perm16, hw, hb, (float*)d_out);
}

// Round 25
// 183.548 us; speedup vs baseline: 1.0616x; 1.0034x over previous
//
#include <hip/hip_runtime.h>
#include <math.h>

#define PI_F 3.14159265358979323846f

typedef __attribute__((ext_vector_type(8))) _Float16 half8;
typedef __attribute__((ext_vector_type(4))) _Float16 half4;
typedef __attribute__((ext_vector_type(4))) float f32x4;

// ---------------------------------------------------------------------------
// Unified prep kernel, grid 3153x256:
//  [0,2380)    x (256,3,64,64) fp32 -> X4P (256,70,68,4) fp16, zero border
//  [2380,2640) conv weight transforms (channel-blocked fp16)
//  [2640,3152) fc1 weight transform (NCHW-k -> NHWC-k fp16)
//  [3152]      quantum prep: 60 Rot matrices + 6x1024 u16 perm table
// ---------------------------------------------------------------------------
__global__ __launch_bounds__(256) void prep_kernel(
    const float* __restrict__ x, _Float16* __restrict__ X4P,
    const float* __restrict__ w1, const float* __restrict__ w2,
    const float* __restrict__ w3, const float* __restrict__ w4,
    _Float16* __restrict__ t1, _Float16* __restrict__ t2,
    _Float16* __restrict__ t3, _Float16* __restrict__ t4,
    const float* __restrict__ f1w, _Float16* __restrict__ w1t,
    const float* __restrict__ qw, float* __restrict__ rotm,
    unsigned short* __restrict__ perm)
{
    const int b = blockIdx.x;
    const int t = threadIdx.x;
    if (b < 2380) {
        int pp = (b * 256 + t) * 2;          // 2 pixels per thread
        half8 o;
        #pragma unroll
        for (int j = 0; j < 2; ++j) {
            int p = pp + j;
            int n = p / 4760;
            int rem = p - n * 4760;
            int yp = rem / 68, xp = rem - (rem / 68) * 68;
            int gy = yp - 2, gx = xp - 2;
            float v0 = 0.f, v1 = 0.f, v2 = 0.f;
            if (gy >= 0 && gy < 64 && gx >= 0 && gx < 64) {
                const float* xb = x + (size_t)n * 12288 + gy * 64 + gx;
                v0 = xb[0]; v1 = xb[4096]; v2 = xb[8192];
            }
            o[j * 4 + 0] = (_Float16)v0;
            o[j * 4 + 1] = (_Float16)v1;
            o[j * 4 + 2] = (_Float16)v2;
            o[j * 4 + 3] = (_Float16)0.f;
        }
        *(half8*)&X4P[(size_t)pp * 4] = o;
    } else if (b < 2640) {
        int idx = (b - 2380) * 256 + t;
        if (idx < 9216) {               // conv2: K=288, 1 group
            int j = idx & 7, co = (idx >> 3) & 31, k8 = idx >> 8;
            int k = k8 * 8 + j, tap = k >> 5, ci = k & 31;
            t2[idx] = (_Float16)w2[(size_t)(co * 32 + ci) * 9 + tap];
        } else if (idx < 27648) {       // conv3: 2 cout groups
            int e = idx - 9216;
            int j = e & 7, co = (e >> 3) & 31, r = e >> 8;
            int k8 = r % 36, gg = r / 36;
            int k = k8 * 8 + j, tap = k >> 5, ci = k & 31;
            t3[e] = (_Float16)w3[(size_t)((gg * 32 + co) * 32 + ci) * 9 + tap];
        } else if (idx < 64512) {       // conv4: 2 cout groups x 2 ci-chunks
            int e = idx - 27648;
            int j = e & 7, co = (e >> 3) & 31, r = e >> 8;
            int k8 = r % 36, gc = r / 36;
            int g = gc >> 1, cc = gc & 1;
            int kl = k8 * 8 + j, tap = kl >> 5, ci = cc * 32 + (kl & 31);
            t4[e] = (_Float16)w4[(size_t)((g * 32 + co) * 64 + ci) * 9 + tap];
        } else if (idx < 66560) {       // conv1: K=64 padded
            int e = idx - 64512;
            int j = e & 7, co = (e >> 3) & 31, k8 = e >> 8;
            int k = k8 * 8 + j, tap = k >> 2, ci = k & 3;
            t1[e] = (_Float16)((tap < 9 && ci < 3) ? w1[(size_t)(co * 3 + ci) * 9 + tap] : 0.f);
        }
    } else if (b < 3152) {
        __shared__ float lds[64][65];
        int b2 = b - 2640;
        const int yx0 = (b2 & 3) * 64;
        const int j = b2 >> 2;
        #pragma unroll
        for (int i = 0; i < 16; ++i) {
            int idx = t + 256 * i;
            int c = idx >> 6, yxl = idx & 63;
            lds[c][yxl] = f1w[(size_t)j * 16384 + c * 256 + yx0 + yxl];
        }
        __syncthreads();
        #pragma unroll
        for (int i = 0; i < 2; ++i) {
            int idx = t + 256 * i;
            int yxl = idx >> 3, c8 = idx & 7;
            half8 h;
            #pragma unroll
            for (int jj = 0; jj < 8; ++jj)
                h[jj] = (_Float16)lds[c8 * 8 + jj][yxl];
            *(half8*)&w1t[(size_t)j * 16384 + (size_t)(yx0 + yxl) * 64 + c8 * 8] = h;
        }
    } else {
        if (t < 60) {
            float phi = qw[t * 3], th = qw[t * 3 + 1], om = qw[t * 3 + 2];
            float c = cosf(0.5f * th), s = sinf(0.5f * th);
            float apo = 0.5f * (phi + om), amo = 0.5f * (phi - om);
            float cpo = cosf(apo), spo = sinf(apo);
            float cmo = cosf(amo), smo = sinf(amo);
            rotm[t * 8 + 0] = cpo * c;  rotm[t * 8 + 1] = -spo * c;
            rotm[t * 8 + 2] = -cmo * s; rotm[t * 8 + 3] = -smo * s;
            rotm[t * 8 + 4] = cmo * s;  rotm[t * 8 + 5] = -smo * s;
            rotm[t * 8 + 6] = cpo * c;  rotm[t * 8 + 7] = spo * c;
        }
        for (int e = t; e < 6144; e += 256) {
            int layer = e >> 10, i = e & 1023;
            int r = layer % 9 + 1;
            int jdx = i;
            for (int w = 9; w >= 0; --w) {
                int tt = (w + r) % 10;
                int pc = 9 - w, pt_ = 9 - tt;
                jdx ^= ((jdx >> pc) & 1) << pt_;
            }
            perm[e] = (unsigned short)jdx;
        }
    }
}

// ---------------------------------------------------------------------------
// conv1: conv1 via MFMA from X4P -> Yg = fp16(conv1+bias) NHWC (256,64,64,32)
// + BN1 partials. Y packed through LDS for coalesced half8 stores.
// ---------------------------------------------------------------------------
__global__ __launch_bounds__(256) void conv1_stats_kernel(
    const _Float16* __restrict__ X4P, const _Float16* __restrict__ w1m,
    const float* __restrict__ bias, _Float16* __restrict__ Yg,
    float* __restrict__ partials)
{
    constexpr int TC = 66, TR = 6;
    constexpr int NPIX = (TR + 1) * TC;     // 462
    __shared__ __align__(16) _Float16 s_in[NPIX * 4];
    __shared__ __align__(16) _Float16 s_w[2048];
    __shared__ __align__(16) _Float16 s_y[256 * 32];   // 16 KB
    __shared__ float s_red[64];

    const int t = threadIdx.x;
    const int row0 = blockIdx.x * 4;
    const int n = blockIdx.z;

    *(half8*)&s_w[t * 8] = *(const half8*)&w1m[t * 8];

    for (int p = t; p < NPIX; p += 256) {
        int col = p % TC, r = p / TC;
        uint2 u = make_uint2(0u, 0u);
        if (r < TR) {
            size_t pb = ((size_t)(n * 70 + row0 + r + 1) * 68 + col + 1) * 4;
            u = *(const uint2*)&X4P[pb];
        }
        *(uint2*)&s_in[p * 4] = u;
    }
    if (t < 64) s_red[t] = 0.f;
    __syncthreads();

    const int w = t >> 6, l = t & 63;
    const int lm = l & 15, lg = l >> 4;
    int pA[4];
    #pragma unroll
    for (int f = 0; f < 4; ++f) {
        int m = w * 64 + f * 16 + lm;
        pA[f] = (m >> 6) * TC + (m & 63);
    }
    f32x4 zero4 = {0.f, 0.f, 0.f, 0.f};
    f32x4 acc[4][2];
    #pragma unroll
    for (int f = 0; f < 4; ++f) { acc[f][0] = zero4; acc[f][1] = zero4; }

    {
        const int t0 = lg * 2;
        const int off0 = (t0 / 3) * TC + (t0 % 3);
        const int off1 = ((t0 + 1) / 3) * TC + ((t0 + 1) % 3);
        half8 b0 = *(const half8*)&s_w[(lg * 32 + lm) * 8];
        half8 b1 = *(const half8*)&s_w[(lg * 32 + 16 + lm) * 8];
        #pragma unroll
        for (int f = 0; f < 4; ++f) {
            half4 alo = *(const half4*)&s_in[(pA[f] + off0) * 4];
            half4 ahi = *(const half4*)&s_in[(pA[f] + off1) * 4];
            half8 a;
            #pragma unroll
            for (int j = 0; j < 4; ++j) { a[j] = alo[j]; a[4 + j] = ahi[j]; }
            acc[f][0] = __builtin_amdgcn_mfma_f32_16x16x32_f16(a, b0, acc[f][0], 0, 0, 0);
            acc[f][1] = __builtin_amdgcn_mfma_f32_16x16x32_f16(a, b1, acc[f][1], 0, 0, 0);
        }
    }
    {
        half8 b0 = *(const half8*)&s_w[((4 + lg) * 32 + lm) * 8];
        half8 b1 = *(const half8*)&s_w[((4 + lg) * 32 + 16 + lm) * 8];
        #pragma unroll
        for (int f = 0; f < 4; ++f) {
            half8 a;
            #pragma unroll
            for (int j = 0; j < 8; ++j) a[j] = (_Float16)0.f;
            if (lg == 0) {
                half4 alo = *(const half4*)&s_in[(pA[f] + 134) * 4];
                half4 ahi = *(const half4*)&s_in[(pA[f] + 198) * 4];
                #pragma unroll
                for (int j = 0; j < 4; ++j) { a[j] = alo[j]; a[4 + j] = ahi[j]; }
            }
            acc[f][0] = __builtin_amdgcn_mfma_f32_16x16x32_f16(a, b0, acc[f][0], 0, 0, 0);
            acc[f][1] = __builtin_amdgcn_mfma_f32_16x16x32_f16(a, b1, acc[f][1], 0, 0, 0);
        }
    }

    float bv0 = bias[lm];
    float bv1 = bias[16 + lm];
    float s0 = 0.f, s20 = 0.f, s1 = 0.f, s21 = 0.f;
    #pragma unroll
    for (int f = 0; f < 4; ++f) {
        #pragma unroll
        for (int r = 0; r < 4; ++r) {
            float v0 = acc[f][0][r] + bv0;
            float v1 = acc[f][1][r] + bv1;
            int p_loc = w * 64 + f * 16 + lg * 4 + r;
            s_y[p_loc * 32 + lm] = (_Float16)v0;
            s_y[p_loc * 32 + 16 + lm] = (_Float16)v1;
            s0 += v0; s20 += v0 * v0;
            s1 += v1; s21 += v1 * v1;
        }
    }
    s0 += __shfl_xor(s0, 16);  s0 += __shfl_xor(s0, 32);
    s1 += __shfl_xor(s1, 16);  s1 += __shfl_xor(s1, 32);
    s20 += __shfl_xor(s20, 16); s20 += __shfl_xor(s20, 32);
    s21 += __shfl_xor(s21, 16); s21 += __shfl_xor(s21, 32);
    if (l < 16) {
        atomicAdd(&s_red[lm], s0);
        atomicAdd(&s_red[16 + lm], s1);
        atomicAdd(&s_red[32 + lm], s20);
        atomicAdd(&s_red[48 + lm], s21);
    }
    __syncthreads();

    // coalesced Y store: 4 rows x 64 cols x 32 ch contiguous
    {
        _Float16* Yb = Yg + ((size_t)(n * 64 + row0) * 64) * 32;
        #pragma unroll
        for (int i = 0; i < 4; ++i) {
            int idx = t + 256 * i;
            *(half8*)&Yb[(size_t)idx * 8] = *(const half8*)&s_y[idx * 8];
        }
    }
    if (t < 64)
        partials[((size_t)n * 16 + blockIdx.x) * 64 + t] = s_red[t];
}

// ---------------------------------------------------------------------------
// conv2 FUSED v9: slice-major LDS (padded slice stride 666 px) for single
// ds_read_b128 A-fragments + c8-fastest coalesced staging with incremental
// py/px (no per-item div). LDS 42.6 KB, 3 blocks/CU. 512 thr, ROWS=8;
// grid (8,1,256).
// ---------------------------------------------------------------------------
__global__ __launch_bounds__(512, 6) void conv2_fused_kernel(
    const _Float16* __restrict__ Yg, const _Float16* __restrict__ ssh1,
    const _Float16* __restrict__ wt2, const float* __restrict__ c2bias,
    _Float16* __restrict__ out0, _Float16* __restrict__ out1,
    float* __restrict__ partials)
{
    constexpr int COUT = 32, MF = 4, NB = 2;
    constexpr int ROWS = 8;
    constexpr int TC = 66, NPIX = 10 * 66;         // 660
    constexpr int SLICEP = 666;                    // padded slice stride (px)
    __shared__ __align__(16) _Float16 s_in[4 * SLICEP * 8];   // 42,624 B
    __shared__ float s_red[64];

    const int t = threadIdx.x;
    const int row0 = blockIdx.x * ROWS;
    const int n = blockIdx.z;
    const int w = t >> 6, l = t & 63;
    const int lm = l & 15, lg = l >> 4;

    if (t < 64) s_red[t] = 0.f;

    // ---- stage relu(bn1(Y)) tile: c8-fastest (coalesced global reads) ----
    {
        const int c8 = t & 3;                       // constant: 512 % 4 == 0
        half8 sc = *(const half8*)&ssh1[c8 * 8];
        half8 sh = *(const half8*)&ssh1[32 + c8 * 8];
        int p = t >> 2;                             // [0,128)
        int py = p / 66;                            // single div at entry
        int px = p - py * 66;
        for (; p < NPIX; p += 128) {
            int gy = row0 - 1 + py, gx = px - 1;
            half8 v;
            #pragma unroll
            for (int j = 0; j < 8; ++j) v[j] = (_Float16)0.f;
            if (gy >= 0 && gy < 64 && gx >= 0 && gx < 64) {
                half8 y = *(const half8*)&Yg[(((size_t)n * 64 + gy) * 64 + gx) * 32 + c8 * 8];
                #pragma unroll
                for (int j = 0; j < 8; ++j) {
                    _Float16 f = y[j] * sc[j] + sh[j];
                    v[j] = f > (_Float16)0.f ? f : (_Float16)0.f;
                }
            }
            *(half8*)&s_in[(c8 * SLICEP + p) * 8] = v;
            // p += 128 => py += 1, px += 62 (with carry)
            py += 1; px += 62;
            if (px >= 66) { px -= 66; py += 1; }
        }
    }
    __syncthreads();

    // ---- conv2 main compute: wave = output row (row0+w), columns f*16+lm ----
    int pA[MF];
    #pragma unroll
    for (int f = 0; f < MF; ++f)
        pA[f] = w * TC + f * 16 + lm;
    f32x4 zero4 = {0.f, 0.f, 0.f, 0.f};
    f32x4 acc[MF][NB];
    #pragma unroll
    for (int f = 0; f < MF; ++f)
        #pragma unroll
        for (int nb = 0; nb < NB; ++nb) acc[f][nb] = zero4;

    #pragma unroll
    for (int tap = 0; tap < 9; ++tap) {
        const int dy = tap / 3, dx = tap % 3;
        const int poff = dy * TC + dx;
        half8 b[NB];
        #pragma unroll
        for (int nb = 0; nb < NB; ++nb) {
            int col = nb * 16 + lm;
            b[nb] = *(const half8*)&wt2[((tap * 4 + lg) * 32 + col) * 8];
        }
        #pragma unroll
        for (int f = 0; f < MF; ++f) {
            int p = pA[f] + poff;
            half8 a = *(const half8*)&s_in[(lg * SLICEP + p) * 8];
            #pragma unroll
            for (int nb = 0; nb < NB; ++nb)
                acc[f][nb] = __builtin_amdgcn_mfma_f32_16x16x32_f16(a, b[nb], acc[f][nb], 0, 0, 0);
        }
    }

    // ---- bias fold + stats (registers only) ----
    float bv[NB], s[NB], s2[NB];
    #pragma unroll
    for (int nb = 0; nb < NB; ++nb) {
        bv[nb] = c2bias[nb * 16 + lm];
        s[nb] = 0.f; s2[nb] = 0.f;
    }
    #pragma unroll
    for (int f = 0; f < MF; ++f) {
        #pragma unroll
        for (int nb = 0; nb < NB; ++nb) {
            #pragma unroll
            for (int r = 0; r < 4; ++r) {
                float v = acc[f][nb][r] + bv[nb];
                acc[f][nb][r] = v;
                s[nb] += v; s2[nb] += v * v;
            }
        }
    }
    #pragma unroll
    for (int nb = 0; nb < NB; ++nb) {
        s[nb] += __shfl_xor(s[nb], 16);  s[nb] += __shfl_xor(s[nb], 32);
        s2[nb] += __shfl_xor(s2[nb], 16); s2[nb] += __shfl_xor(s2[nb], 32);
    }
    if (l < 16) {
        #pragma unroll
        for (int nb = 0; nb < NB; ++nb) {
            atomicAdd(&s_red[nb * 16 + lm], s[nb]);
            atomicAdd(&s_red[32 + nb * 16 + lm], s2[nb]);
        }
    }

    // ---- pool: h-pool in lane -> pk rows -> vertical gather -> stores ----
    {
        __syncthreads();                    // all MFMA reads of s_in done
        _Float16* pk = s_in;                // [8 rows][32 xp][32 ch] min, +8192 max
        #pragma unroll
        for (int nb = 0; nb < NB; ++nb) {
            #pragma unroll
            for (int f = 0; f < MF; ++f) {
                float v0 = acc[f][nb][0], v1 = acc[f][nb][1];
                float v2 = acc[f][nb][2], v3 = acc[f][nb][3];
                int xp0 = f * 8 + lg * 2;
                int o0 = (w * 32 + xp0) * COUT + nb * 16 + lm;
                int o1 = (w * 32 + xp0 + 1) * COUT + nb * 16 + lm;
                pk[o0] = (_Float16)fminf(v0, v1);
                pk[8192 + o0] = (_Float16)fmaxf(v0, v1);
                pk[o1] = (_Float16)fminf(v2, v3);
                pk[8192 + o1] = (_Float16)fmaxf(v2, v3);
            }
        }
        __syncthreads();
        // vertical gather: 4 pooled rows x 32 xp x 4 c8 = 512 threads
        int hp_row = t >> 7, rem = t & 127;
        int xp = rem >> 2, c8 = rem & 3;
        half8 mnA = *(const half8*)&pk[((2 * hp_row) * 32 + xp) * COUT + c8 * 8];
        half8 mnB = *(const half8*)&pk[((2 * hp_row + 1) * 32 + xp) * COUT + c8 * 8];
        half8 mxA = *(const half8*)&pk[8192 + ((2 * hp_row) * 32 + xp) * COUT + c8 * 8];
        half8 mxB = *(const half8*)&pk[8192 + ((2 * hp_row + 1) * 32 + xp) * COUT + c8 * 8];
        half8 mn, mx;
        #pragma unroll
        for (int j = 0; j < 8; ++j) {
            mn[j] = mnA[j] < mnB[j] ? mnA[j] : mnB[j];
            mx[j] = mxA[j] > mxB[j] ? mxA[j] : mxB[j];
        }
        size_t ob = (((size_t)n * 32 + (row0 >> 1) + hp_row) * 32 + xp) * COUT + c8 * 8;
        *(half8*)&out0[ob] = mn;
        *(half8*)&out1[ob] = mx;
    }

    __syncthreads();
    if (t < 64) {
        size_t bid = (size_t)n * gridDim.x + blockIdx.x;
        partials[bid * 64 + t] = s_red[t];
    }
}

// ---------------------------------------------------------------------------
// Implicit-GEMM 3x3 conv via MFMA (single-pass staging). Used for conv3/conv4.
// ---------------------------------------------------------------------------
template<int BLOCK, int W, int CIN, int COUT, int MF, int NB,
         bool MMIN, bool POOL>
__global__ __launch_bounds__(BLOCK, (BLOCK == 512 ? 4 : 3)) void conv_mfma_kernel(
    const _Float16* __restrict__ in0, const _Float16* __restrict__ in1,
    const _Float16* __restrict__ coef, const _Float16* __restrict__ wt,
    const float* __restrict__ bias,
    _Float16* __restrict__ out0, _Float16* __restrict__ out1,
    float* __restrict__ partials)
{
    constexpr int H = W;
    constexpr int NWAVE = BLOCK / 64;
    constexpr int SPW = MF * 16;
    constexpr int ROWS = NWAVE * SPW / W;
    constexpr int TR = ROWS + 2;
    constexpr int TC = W + 2;
    constexpr int NPIX = TR * TC;
    constexpr int NCH = CIN / 32;
    constexpr int C8N = CIN / 8;
    constexpr int KC = 288;
    constexpr int COUTB = NB * 16;
    __shared__ __align__(16) _Float16 s_in[NPIX * CIN];
    __shared__ float s_red[2 * COUTB];

    const int t = threadIdx.x;
    const int row0 = blockIdx.x * ROWS;
    const int n = blockIdx.z;

    const int w = t >> 6, l = t & 63;
    const int lm = l & 15, lg = l >> 4;
    int pA[MF];
    #pragma unroll
    for (int f = 0; f < MF; ++f) {
        int m = w * SPW + f * 16 + lm;
        pA[f] = (m / W) * TC + (m % W);
    }
    f32x4 zero4 = {0.f, 0.f, 0.f, 0.f};
    f32x4 acc[MF][NB];
    #pragma unroll
    for (int f = 0; f < MF; ++f)
        #pragma unroll
        for (int nb = 0; nb < NB; ++nb) acc[f][nb] = zero4;
    if (t < 2 * COUTB) s_red[t] = 0.f;

    for (int idx = t; idx < NPIX * C8N; idx += BLOCK) {
        int c8 = idx % C8N;
        int p = idx / C8N;
        int col = p % TC, r = p / TC;
        int gy = row0 + r - 1, gx = col - 1;
        half8 v;
        #pragma unroll
        for (int j = 0; j < 8; ++j) v[j] = (_Float16)0.f;
        if (gy >= 0 && gy < H && gx >= 0 && gx < W) {
            size_t gidx = (((size_t)n * H + gy) * W + gx) * CIN + c8 * 8;
            if (MMIN) {
                half8 mn = *(const half8*)&in0[gidx];
                half8 mx = *(const half8*)&in1[gidx];
                half8 sa = *(const half8*)&coef[c8 * 8];
                half8 sb = *(const half8*)&coef[CIN + c8 * 8];
                half8 sh = *(const half8*)&coef[2 * CIN + c8 * 8];
                #pragma unroll
                for (int j = 0; j < 8; ++j) {
                    _Float16 f = mx[j] * sa[j] + mn[j] * sb[j] + sh[j];
                    v[j] = f > (_Float16)0.f ? f : (_Float16)0.f;
                }
            } else {
                v = *(const half8*)&in0[gidx];
                if (coef) {
                    half8 sc = *(const half8*)&coef[c8 * 8];
                    half8 sh = *(const half8*)&coef[CIN + c8 * 8];
                    #pragma unroll
                    for (int j = 0; j < 8; ++j) {
                        _Float16 f = v[j] * sc[j] + sh[j];
                        v[j] = f > (_Float16)0.f ? f : (_Float16)0.f;
                    }
                }
            }
        }
        *(half8*)&s_in[(c8 * NPIX + p) * 8] = v;
    }
    __syncthreads();

    #pragma unroll
    for (int tap = 0; tap < 9; ++tap) {
        const int dy = tap / 3, dx = tap % 3;
        const int poff = dy * TC + dx;
        #pragma unroll
        for (int cc = 0; cc < NCH; ++cc) {
            half8 b[NB];
            #pragma unroll
            for (int nb = 0; nb < NB; ++nb) {
                int cog = nb * 16 + lm;
                int gg = cog >> 5, col = cog & 31;
                const _Float16* wp = wt + (size_t)(gg * NCH + cc) * KC * 32;
                b[nb] = *(const half8*)&wp[((tap * 4 + lg) * 32 + col) * 8];
            }
            #pragma unroll
            for (int f = 0; f < MF; ++f) {
                half8 a = *(const half8*)&s_in[((cc * 4 + lg) * NPIX + pA[f] + poff) * 8];
                #pragma unroll
                for (int nb = 0; nb < NB; ++nb)
                    acc[f][nb] = __builtin_amdgcn_mfma_f32_16x16x32_f16(a, b[nb], acc[f][nb], 0, 0, 0);
            }
        }
    }

    float bv[NB], s[NB], s2[NB];
    #pragma unroll
    for (int nb = 0; nb < NB; ++nb) {
        bv[nb] = bias[nb * 16 + lm];
        s[nb] = 0.f; s2[nb] = 0.f;
    }
    #pragma unroll
    for (int f = 0; f < MF; ++f) {
        #pragma unroll
        for (int r = 0; r < 4; ++r) {
            int m = w * SPW + f * 16 + lg * 4 + r;
            int yy = row0 + m / W, xo = m % W;
            size_t base = (((size_t)n * H + yy) * W + xo) * COUT;
            #pragma unroll
            for (int nb = 0; nb < NB; ++nb) {
                float v = acc[f][nb][r] + bv[nb];
                if (!POOL) out0[base + nb * 16 + lm] = (_Float16)v;
                s[nb] += v; s2[nb] += v * v;
            }
        }
    }
    #pragma unroll
    for (int nb = 0; nb < NB; ++nb) {
        s[nb] += __shfl_xor(s[nb], 16);  s[nb] += __shfl_xor(s[nb], 32);
        s2[nb] += __shfl_xor(s2[nb], 16); s2[nb] += __shfl_xor(s2[nb], 32);
    }
    if (l < 16) {
        #pragma unroll
        for (int nb = 0; nb < NB; ++nb) {
            atomicAdd(&s_red[nb * 16 + lm], s[nb]);
            atomicAdd(&s_red[COUTB + nb * 16 + lm], s2[nb]);
        }
    }

    if (POOL) {
        constexpr int FH = MF / 2;
        constexpr int PPIX = (ROWS / 2) * (W / 2);
        static_assert(2 * PPIX * COUT <= NPIX * CIN, "pool pack fits in s_in");
        __syncthreads();
        _Float16* pk = s_in;
        #pragma unroll
        for (int nb = 0; nb < NB; ++nb) {
            #pragma unroll
            for (int f = 0; f < FH; ++f) {
                #pragma unroll
                for (int rp = 0; rp < 2; ++rp) {
                    float a0 = acc[f][nb][2 * rp] + bv[nb];
                    float a1 = acc[f][nb][2 * rp + 1] + bv[nb];
                    float a2 = acc[f + FH][nb][2 * rp] + bv[nb];
                    float a3 = acc[f + FH][nb][2 * rp + 1] + bv[nb];
                    float mn = fminf(fminf(a0, a1), fminf(a2, a3));
                    float mx = fmaxf(fmaxf(a0, a1), fmaxf(a2, a3));
                    int xp = f * 8 + lg * 2 + rp;
                    int o = (w * (W / 2) + xp) * COUT + nb * 16 + lm;
                    pk[o] = (_Float16)mn;
                    pk[PPIX * COUT + o] = (_Float16)mx;
                }
            }
        }
        __syncthreads();
        size_t gb = (((size_t)n * (H / 2) + (row0 >> 1)) * (W / 2)) * COUT;
        for (int idx = t; idx < PPIX * COUT / 8; idx += BLOCK) {
            *(half8*)&out0[gb + (size_t)idx * 8] = *(const half8*)&pk[idx * 8];
            *(half8*)&out1[gb + (size_t)idx * 8] = *(const half8*)&pk[(PPIX * COUT + idx * 8)];
        }
    }

    __syncthreads();
    if (t < 2 * COUTB) {
        size_t bid = (size_t)n * gridDim.x + blockIdx.x;
        partials[bid * 2 * COUTB + t] = s_red[t];
    }
}

// ---------------------------------------------------------------------------
// Reduce per-block partials -> BN coefficients. Record = [sum C | sumsq C].
// ---------------------------------------------------------------------------
__global__ __launch_bounds__(256) void bn_finalize_kernel(
    const float* __restrict__ partials, int nx, float inv_count,
    const float* __restrict__ gamma, const float* __restrict__ beta,
    float* __restrict__ ss, _Float16* __restrict__ ssh,
    _Float16* __restrict__ sab, int COUT)
{
    const int c = blockIdx.x;
    const int t = threadIdx.x;
    float sum = 0.f, sq = 0.f;
    int total = 256 * nx;
    for (int e = t; e < total; e += 256) {
        size_t off = (size_t)e * 2 * COUT;
        sum += partials[off + c];
        sq  += partials[off + COUT + c];
    }
    #pragma unroll
    for (int off = 32; off > 0; off >>= 1) {
        sum += __shfl_xor(sum, off);
        sq  += __shfl_xor(sq, off);
    }
    __shared__ float rs[4], rq[4];
    if ((t & 63) == 0) { rs[t >> 6] = sum; rq[t >> 6] = sq; }
    __syncthreads();
    if (t == 0) {
        sum = rs[0] + rs[1] + rs[2] + rs[3];
        sq  = rq[0] + rq[1] + rq[2] + rq[3];
        float mean = sum * inv_count;
        float var = sq * inv_count - mean * mean;
        float scale = gamma[c] * rsqrtf(var + 1e-5f);
        float shift = beta[c] - mean * scale;
        ss[c] = scale;
        ss[COUT + c] = shift;
        if (ssh) {
            ssh[c] = (_Float16)scale;
            ssh[COUT + c] = (_Float16)shift;
        }
        if (sab) {
            sab[c] = (_Float16)(scale > 0.f ? scale : 0.f);
            sab[COUT + c] = (_Float16)(scale > 0.f ? 0.f : scale);
            sab[2 * COUT + c] = (_Float16)shift;
        }
    }
}

// ---------------------------------------------------------------------------
// fc1 MFMA GEMM (K-split): A = relu(bn4(pooled minmax pair)) on the fly.
// ---------------------------------------------------------------------------
__global__ __launch_bounds__(256) void fc1_mfma_kernel(
    const _Float16* __restrict__ Amin, const _Float16* __restrict__ Amax,
    const _Float16* __restrict__ sab, const _Float16* __restrict__ Bw,
    float* __restrict__ hp)
{
    __shared__ __align__(16) _Float16 As[64][72];
    __shared__ __align__(16) _Float16 Bs[128][72];
    const int t = threadIdx.x;
    const int mt = blockIdx.x;
    const int kc = blockIdx.y;
    const int w = t >> 6, l = t & 63;
    const int lm = l & 15, lg = l >> 4;

    f32x4 zero4 = {0.f, 0.f, 0.f, 0.f};
    f32x4 acc[8];
    #pragma unroll
    for (int nb = 0; nb < 8; ++nb) acc[nb] = zero4;

    const size_t a_base = (size_t)(mt * 64) * 16384 + (size_t)kc * 512;
    const size_t b_base = (size_t)kc * 512;

    for (int p = 0; p < 8; ++p) {
        __syncthreads();
        #pragma unroll
        for (int i = 0; i < 2; ++i) {
            int idx = t + 256 * i;
            int r = idx >> 3, c8 = idx & 7;
            size_t off = a_base + (size_t)r * 16384 + p * 64 + c8 * 8;
            half8 mn = *(const half8*)&Amin[off];
            half8 mx = *(const half8*)&Amax[off];
            half8 sa = *(const half8*)&sab[c8 * 8];
            half8 sb = *(const half8*)&sab[64 + c8 * 8];
            half8 sh = *(const half8*)&sab[128 + c8 * 8];
            half8 v;
            #pragma unroll
            for (int j = 0; j < 8; ++j) {
                _Float16 f = mx[j] * sa[j] + mn[j] * sb[j] + sh[j];
                v[j] = f > (_Float16)0.f ? f : (_Float16)0.f;
            }
            *(half8*)&As[r][c8 * 8] = v;
        }
        #pragma unroll
        for (int i = 0; i < 4; ++i) {
            int idx = t + 256 * i;
            int r = idx >> 3, c8 = idx & 7;
            *(half8*)&Bs[r][c8 * 8] =
                *(const half8*)&Bw[b_base + (size_t)r * 16384 + p * 64 + c8 * 8];
        }
        __syncthreads();
        #pragma unroll
        for (int ks = 0; ks < 64; ks += 32) {
            half8 a = *(const half8*)&As[w * 16 + lm][ks + lg * 8];
            #pragma unroll
            for (int nb = 0; nb < 8; ++nb) {
                half8 b = *(const half8*)&Bs[nb * 16 + lm][ks + lg * 8];
                acc[nb] = __builtin_amdgcn_mfma_f32_16x16x32_f16(a, b, acc[nb], 0, 0, 0);
            }
        }
    }
    #pragma unroll
    for (int nb = 0; nb < 8; ++nb) {
        #pragma unroll
        for (int r = 0; r < 4; ++r) {
            int row = mt * 64 + w * 16 + lg * 4 + r;
            hp[((size_t)kc * 256 + row) * 128 + nb * 16 + lm] = acc[nb][r];
        }
    }
}

// ---------------------------------------------------------------------------
// fc1 reduce + relu + fc2 + quantum circuit + head, one block per batch n.
// 256 threads = 4 waves; quantum state spread over 4 waves (4 amps/lane):
// amp = (r<<8)|(wv<<6)|lane. Gates: bits 8-9 in-register, bits 6-7 LDS
// cross-wave exchange, bits 0-5 shfl_xor.
// ---------------------------------------------------------------------------
__global__ __launch_bounds__(256) void fcq_kernel(
    const float* __restrict__ hp, const float* __restrict__ f1b,
    const float* __restrict__ f2w, const float* __restrict__ f2b,
    const float* __restrict__ rotm, const unsigned short* __restrict__ perm,
    const float* __restrict__ head_w, const float* __restrict__ head_b,
    float* __restrict__ outp)
{
    __shared__ float lre[1024];
    __shared__ float lim[1024];
    __shared__ float hl[128];
    __shared__ float xql[10];
    const int n = blockIdx.x;
    const int t = threadIdx.x;
    const int l = t & 63;
    const int wv = t >> 6;

    // ---- fc1 reduce + bias + relu (exact original order, t<128) ----
    if (t < 128) {
        float s = f1b[t];
        #pragma unroll
        for (int kc = 0; kc < 32; ++kc) s += hp[((size_t)kc * 256 + n) * 128 + t];
        hl[t] = fmaxf(0.f, s);
    }
    __syncthreads();
    // ---- fc2 ----
    if (t < 10) {
        float o = f2b[t];
        #pragma unroll 4
        for (int k = 0; k < 128; ++k) o += f2w[t * 128 + k] * hl[k];
        xql[t] = o;
    }
    __syncthreads();

    // ---- quantum: 4 amps/lane, amp = (r<<8)|(wv<<6)|l ----
    const int ampb = (wv << 6) | l;          // low 8 bits of amp (r adds <<8)
    float ar[4], ai[4];
    #pragma unroll
    for (int r = 0; r < 4; ++r) { ar[r] = 0.f; ai[r] = 0.f; }
    if (t == 0) ar[0] = 1.f;

    // RY embedding layer (real amplitudes)
    #pragma unroll
    for (int w = 0; w < 10; ++w) {
        float th = 0.5f * PI_F * xql[w];
        float c = cosf(th), s = sinf(th);
        const int k = 9 - w;
        if (k >= 8) {
            const int b = k - 8;
            #pragma unroll
            for (int r = 0; r < 4; ++r) {
                if (!(r & (1 << b))) {
                    int r1 = r | (1 << b);
                    float a0 = ar[r], a1 = ar[r1];
                    ar[r]  = c * a0 - s * a1;
                    ar[r1] = s * a0 + c * a1;
                }
            }
        } else if (k >= 6) {
            #pragma unroll
            for (int r = 0; r < 4; ++r) lre[(r << 8) | ampb] = ar[r];
            __syncthreads();
            float ss = ((wv >> (k - 6)) & 1) ? s : -s;
            #pragma unroll
            for (int r = 0; r < 4; ++r) {
                float p = lre[((r << 8) | ampb) ^ (1 << k)];
                ar[r] = c * ar[r] + ss * p;
            }
            __syncthreads();
        } else {
            float ss = ((l >> k) & 1) ? s : -s;
            #pragma unroll
            for (int r = 0; r < 4; ++r) {
                float p = __shfl_xor(ar[r], 1 << k);
                ar[r] = c * ar[r] + ss * p;
            }
        }
    }

    #pragma unroll 1
    for (int layer = 0; layer < 6; ++layer) {
        #pragma unroll
        for (int w = 0; w < 10; ++w) {
            const float* m = rotm + (layer * 10 + w) * 8;
            float m00r = m[0], m00i = m[1], m01r = m[2], m01i = m[3];
            float m10r = m[4], m10i = m[5], m11r = m[6], m11i = m[7];
            const int k = 9 - w;
            if (k >= 8) {
                const int b = k - 8;
                #pragma unroll
                for (int r = 0; r < 4; ++r) {
                    if (!(r & (1 << b))) {
                        int r1 = r | (1 << b);
                        float a0r = ar[r], a0i = ai[r];
                        float a1r = ar[r1], a1i = ai[r1];
                        ar[r]  = m00r * a0r - m00i * a0i + m01r * a1r - m01i * a1i;
                        ai[r]  = m00r * a0i + m00i * a0r + m01r * a1i + m01i * a1r;
                        ar[r1] = m10r * a0r - m10i * a0i + m11r * a1r - m11i * a1i;
                        ai[r1] = m10r * a0i + m10i * a0r + m11r * a1i + m11i * a1r;
                    }
                }
            } else if (k >= 6) {
                #pragma unroll
                for (int r = 0; r < 4; ++r) {
                    lre[(r << 8) | ampb] = ar[r];
                    lim[(r << 8) | ampb] = ai[r];
                }
                __syncthreads();
                int bit = (wv >> (k - 6)) & 1;
                float mAr = bit ? m11r : m00r, mAi = bit ? m11i : m00i;
                float mBr = bit ? m10r : m01r, mBi = bit ? m10i : m01i;
                #pragma unroll
                for (int r = 0; r < 4; ++r) {
                    int pa = ((r << 8) | ampb) ^ (1 << k);
                    float pr = lre[pa], pi = lim[pa];
                    float mr = ar[r], mi = ai[r];
                    ar[r] = mAr * mr - mAi * mi + mBr * pr - mBi * pi;
                    ai[r] = mAr * mi + mAi * mr + mBr * pi + mBi * pr;
                }
                __syncthreads();
            } else {
                int bit = (l >> k) & 1;
                float mAr = bit ? m11r : m00r, mAi = bit ? m11i : m00i;
                float mBr = bit ? m10r : m01r, mBi = bit ? m10i : m01i;
                #pragma unroll
                for (int r = 0; r < 4; ++r) {
                    float pr = __shfl_xor(ar[r], 1 << k);
                    float pi = __shfl_xor(ai[r], 1 << k);
                    float mr = ar[r], mi = ai[r];
                    ar[r] = mAr * mr - mAi * mi + mBr * pr - mBi * pi;
                    ai[r] = mAr * mi + mAi * mr + mBr * pi + mBi * pr;
                }
            }
        }
        // layer permutation
        #pragma unroll
        for (int r = 0; r < 4; ++r) {
            lre[(r << 8) | ampb] = ar[r];
            lim[(r << 8) | ampb] = ai[r];
        }
        __syncthreads();
        const unsigned short* pt = perm + layer * 1024;
        #pragma unroll
        for (int r = 0; r < 4; ++r) {
            int ji = pt[(r << 8) | ampb];
            ar[r] = lre[ji];
            ai[r] = lim[ji];
        }
        __syncthreads();
    }

    // ---- Z expectations + head ----
    float S = 0.f, T9 = 0.f, T8 = 0.f;
    #pragma unroll
    for (int r = 0; r < 4; ++r) {
        float pr = ar[r] * ar[r] + ai[r] * ai[r];
        S += pr;
        T9 += (r & 2) ? -pr : pr;       // amp bit9 -> wire 0
        T8 += (r & 1) ? -pr : pr;       // amp bit8 -> wire 1
    }
    float pk[10];
    pk[0] = T9;
    pk[1] = T8;
    pk[2] = ((wv >> 1) & 1) ? -S : S;   // amp bit7 -> wire 2
    pk[3] = (wv & 1) ? -S : S;          // amp bit6 -> wire 3
    #pragma unroll
    for (int w = 4; w < 10; ++w)
        pk[w] = ((l >> (9 - w)) & 1) ? -S : S;
    #pragma unroll
    for (int w = 0; w < 10; ++w) {
        #pragma unroll
        for (int off = 1; off < 64; off <<= 1)
            pk[w] += __shfl_xor(pk[w], off);
    }
    if (l == 0) {
        #pragma unroll
        for (int w = 0; w < 10; ++w) lre[wv * 16 + w] = pk[w];
    }
    __syncthreads();
    if (t < 10) {
        float tot = lre[t] + lre[16 + t] + lre[32 + t] + lre[48 + t];
        lre[64 + t] = tot;
    }
    __syncthreads();
    if (t < 10) {
        float o = head_b[t];
        #pragma unroll
        for (int kk = 0; kk < 10; ++kk) o += lre[64 + kk] * head_w[t * 10 + kk];
        outp[n * 10 + t] = o;
    }
}

// ---------------------------------------------------------------------------
extern "C" void kernel_launch(void* const* d_in, const int* in_sizes, int n_in,
                              void* d_out, int out_size, void* d_ws, size_t ws_size,
                              hipStream_t stream)
{
    const float* x   = (const float*)d_in[0];
    const float* c1w = (const float*)d_in[1];  const float* c1b = (const float*)d_in[2];
    const float* g1  = (const float*)d_in[3];  const float* b1  = (const float*)d_in[4];
    const float* c2w = (const float*)d_in[5];  const float* c2b = (const float*)d_in[6];
    const float* g2  = (const float*)d_in[7];  const float* b2  = (const float*)d_in[8];
    const float* c3w = (const float*)d_in[9];  const float* c3b = (const float*)d_in[10];
    const float* g3  = (const float*)d_in[11]; const float* b3  = (const float*)d_in[12];
    const float* c4w = (const float*)d_in[13]; const float* c4b = (const float*)d_in[14];
    const float* g4  = (const float*)d_in[15]; const float* b4  = (const float*)d_in[16];
    const float* f1w = (const float*)d_in[17]; const float* f1b = (const float*)d_in[18];
    const float* f2w = (const float*)d_in[19]; const float* f2b = (const float*)d_in[20];
    const float* qw  = (const float*)d_in[21];
    const float* hw  = (const float*)d_in[22]; const float* hb  = (const float*)d_in[23];

    float* ws = (float*)d_ws;
    _Float16* H0 = (_Float16*)ws;              // 33,554,432 halves (67 MB)
    _Float16* H1 = H0 + 33554432;              // 33,554,432 halves (67 MB)
    float* part = ws + 33554432;               // 524,288
    float* ss1  = part + 524288;               // 64
    float* ss2  = ss1 + 64;                    // 64
    float* ss3  = ss2 + 64;                    // 128
    float* ss4  = ss3 + 128;                   // 128
    float* hp   = ss4 + 128;                   // 1,048,576
    float* rotm = hp + 1048576;                // 480
    unsigned short* perm16 = (unsigned short*)(rotm + 480);   // 6,144 u16
    _Float16* ssh1 = (_Float16*)(perm16 + 6144);   // 64 halves
    _Float16* ssh3 = ssh1 + 64;                // 128
    _Float16* sab2 = ssh3 + 128;               // 96
    _Float16* sab4 = sab2 + 96;                // 192
    _Float16* wt2  = sab4 + 192;               // 9,216
    _Float16* wt3  = wt2 + 9216;               // 18,432
    _Float16* wt4  = wt3 + 18432;              // 36,864
    _Float16* w1m  = wt4 + 36864;              // 2,048
    _Float16* w1t  = w1m + 2048;               // 2,097,152
    _Float16* X4P  = w1t + 2097152;            // 4,874,240 (256*70*68*4, 9.75 MB)

    // overlays (sequential lifetimes):
    //  Yg (conv1+bias fp16, 256x64x64x32 = 33.5M halves) = H0; dead once conv2
    //  completes; conv3 then writes its output into H0.
    _Float16* Yg    = H0;
    _Float16* minT2 = H1;                      // (256,32,32,32)
    _Float16* maxT2 = H1 + 8388608;
    _Float16* minT4 = H1;                      // (256,16,16,64)
    _Float16* maxT4 = H1 + 4194304;

    // unified one-time prep
    prep_kernel<<<3153, 256, 0, stream>>>(x, X4P, c1w, c2w, c3w, c4w,
                                          w1m, wt2, wt3, wt4, f1w, w1t,
                                          qw, rotm, perm16);

    // conv1: Y = fp16(conv1+bias) -> Yg (H0) + BN1 stats
    conv1_stats_kernel<<<dim3(16, 1, 256), 256, 0, stream>>>(
        X4P, w1m, c1b, Yg, part);
    bn_finalize_kernel<<<32, 256, 0, stream>>>(part, 16, 1.f / 1048576.f,
                                               g1, b1, ss1, ssh1, nullptr, 32);

    // conv2 FUSED v9 (slice-major LDS + coalesced staging): -> minT2/maxT2
    conv2_fused_kernel<<<dim3(8, 1, 256), 512, 0, stream>>>(
        Yg, ssh1, wt2, c2b, minT2, maxT2, part);
    bn_finalize_kernel<<<32, 256, 0, stream>>>(part, 8, 1.f / 1048576.f,
                                               g2, b2, ss2, nullptr, sab2, 32);

    // conv3 (512thr, 64 cout/wave, minmax input): relu(bn2(pool1)) -> H0
    conv_mfma_kernel<512, 32, 32, 64, 4, 4, true, false>
        <<<dim3(2, 1, 256), 512, 0, stream>>>(
        minT2, maxT2, sab2, wt3, c3b, H0, nullptr, part);
    bn_finalize_kernel<<<64, 256, 0, stream>>>(part, 2, 1.f / 262144.f,
                                               g3, b3, ss3, ssh3, nullptr, 64);

    // conv4 (512thr, single-pass CIN=64 staging, packed pooled stores)
    conv_mfma_kernel<512, 32, 64, 64, 4, 4, false, true>
        <<<dim3(2, 1, 256), 512, 0, stream>>>(
        H0, nullptr, ssh3, wt4, c4b, minT4, maxT4, part);
    bn_finalize_kernel<<<64, 256, 0, stream>>>(part, 2, 1.f / 262144.f,
                                               g4, b4, ss4, nullptr, sab4, 64);

    // fc1: MFMA GEMM with on-the-fly relu(bn4(pool2))
    fc1_mfma_kernel<<<dim3(4, 32), 256, 0, stream>>>(minT4, maxT4, sab4, w1t, hp);

    // fc1-reduce + fc2 + quantum circuit (4-wave) + head -> out (256,10)
    fcq_kernel<<<256, 256, 0, stream>>>(hp, f1b, f2w, f2b,
                                        rotm, perm16, hw, hb, (float*)d_out);
}